// Round 6
// baseline (850.097 us; speedup 1.0000x reference)
//
#include <hip/hip_runtime.h>
#include <math.h>

#define THR 256

// ---------------- CSR build ----------------

// Detect whether edge_index buffer is int64 (high words all zero) or int32.
__global__ void k_detect(const int* __restrict__ w, int* __restrict__ flag) {
  int i = blockIdx.x * blockDim.x + threadIdx.x;
  if (i < 4096) {
    if (w[2 * i + 1] != 0) atomicOr(flag, 1);
  }
}

__device__ __forceinline__ int load_idx(const int* __restrict__ w, int pos, int is32) {
  return is32 ? w[pos] : w[2 * pos];
}

__global__ void k_count(const int* __restrict__ ei, const int* __restrict__ flag,
                        int* __restrict__ cnt, int E) {
  int e = blockIdx.x * blockDim.x + threadIdx.x;
  if (e < E) {
    int is32 = *flag;
    int d = load_idx(ei, E + e, is32);
    atomicAdd(&cnt[d], 1);
  }
}

__global__ __launch_bounds__(1024) void k_scan(int* __restrict__ cnt_cur, int* __restrict__ off, int n) {
  __shared__ int part[1024];
  int tid = threadIdx.x;
  int chunk = (n + 1023) / 1024;
  int s0 = tid * chunk;
  int s1 = min(s0 + chunk, n);
  int s = 0;
  for (int i = s0; i < s1; ++i) s += cnt_cur[i];
  part[tid] = s;
  __syncthreads();
  for (int d = 1; d < 1024; d <<= 1) {
    int v = (tid >= d) ? part[tid - d] : 0;
    __syncthreads();
    part[tid] += v;
    __syncthreads();
  }
  int excl = (tid == 0) ? 0 : part[tid - 1];
  for (int i = s0; i < s1; ++i) {
    int c = cnt_cur[i];
    off[i] = excl;
    cnt_cur[i] = excl;   // cursor copy for scatter
    excl += c;
  }
  if (tid == 1023) off[n] = part[1023];
}

__global__ void k_scatter(const int* __restrict__ ei, const int* __restrict__ flag,
                          int* __restrict__ cur, int* __restrict__ pos,
                          int* __restrict__ ssrc, int E) {
  int e = blockIdx.x * blockDim.x + threadIdx.x;
  if (e < E) {
    int is32 = *flag;
    int d = load_idx(ei, E + e, is32);
    int s = load_idx(ei, e, is32);
    int p = atomicAdd(&cur[d], 1);
    pos[e] = p;
    ssrc[p] = s;
  }
}

// ---------------- weight prep ----------------

// WeT rows: layer0 d=0..63 ; layer1 rows 64..127 ; layer2 rows 128..383
__global__ void k_transpose_we(const float* __restrict__ We0, const float* __restrict__ We1,
                               const float* __restrict__ We2, float* __restrict__ WeT) {
  int i = blockIdx.x * blockDim.x + threadIdx.x;
  if (i >= 384 * 16) return;
  int row = i >> 4, k = i & 15;
  float v;
  if (row < 64)        v = We0[k * 64 + row];
  else if (row < 128)  v = We1[k * 64 + (row - 64)];
  else                 v = We2[k * 256 + (row - 128)];
  WeT[i] = v;
}

__global__ void k_fold_att(const float* __restrict__ W, const float* __restrict__ att,
                           float* __restrict__ waj, float* __restrict__ wai,
                           int Cin, int H) {
  int i = blockIdx.x * blockDim.x + threadIdx.x;
  if (i >= Cin * H) return;
  int k = i / H, h = i % H;
  float sj = 0.f, si = 0.f;
  for (int d = 0; d < 64; ++d) {
    float w = W[k * (H * 64) + h * 64 + d];
    sj = fmaf(w, att[h * 192 + d], sj);
    si = fmaf(w, att[h * 192 + 64 + d], si);
  }
  waj[k * H + h] = sj;
  wai[k * H + h] = si;
}

template <int CIN, int H>
__global__ void k_node_dots(const float* __restrict__ xin, const float* __restrict__ waj,
                            const float* __restrict__ wai, float* __restrict__ ajd,
                            float* __restrict__ aid, int N) {
  int n = blockIdx.x * blockDim.x + threadIdx.x;
  if (n >= N) return;
  float sj[H], si[H];
#pragma unroll
  for (int h = 0; h < H; ++h) { sj[h] = 0.f; si[h] = 0.f; }
  const float* xr = xin + (size_t)n * CIN;
#pragma unroll 4
  for (int k = 0; k < CIN; ++k) {
    float xv = xr[k];
#pragma unroll
    for (int h = 0; h < H; ++h) {
      sj[h] = fmaf(xv, waj[k * H + h], sj[h]);
      si[h] = fmaf(xv, wai[k * H + h], si[h]);
    }
  }
#pragma unroll
  for (int h = 0; h < H; ++h) {
    ajd[(size_t)n * H + h] = sj[h];
    aid[(size_t)n * H + h] = si[h];
  }
}

// ---------------- edge scalar ep (4 edges/thread, written in CSR-sorted order) ----------------

// ep[e,h] = sum_d relu(ea[e]·We[:,d]) * a_p[h,d] for all 3 layers.
// 4 edges per thread: each uniform (scalar-cached) weight dword feeds 4 FMAs,
// so VALU issue is ~all useful FMA instead of ~50% overhead.
__global__ __launch_bounds__(256, 4) void k_ep(
    const float* __restrict__ ea, const float* __restrict__ WeT,
    const float* __restrict__ att0, const float* __restrict__ att1,
    const float* __restrict__ att2, const int* __restrict__ pos,
    float* __restrict__ ep0, float* __restrict__ ep1,
    float* __restrict__ ep2, int E) {
  const int t = blockIdx.x * blockDim.x + threadIdx.x;
  const int e0 = t * 4;
  if (e0 >= E) return;

  float ar[4][16];
#pragma unroll
  for (int u = 0; u < 4; ++u) {
    int ee = min(e0 + u, E - 1);   // clamp: redundant compute for tail, stores guarded
    const float4* eav = reinterpret_cast<const float4*>(ea + (size_t)ee * 16);
    float4 A = eav[0], B = eav[1], C = eav[2], D = eav[3];
    ar[u][0] = A.x;  ar[u][1] = A.y;  ar[u][2] = A.z;  ar[u][3] = A.w;
    ar[u][4] = B.x;  ar[u][5] = B.y;  ar[u][6] = B.z;  ar[u][7] = B.w;
    ar[u][8] = C.x;  ar[u][9] = C.y;  ar[u][10] = C.z; ar[u][11] = C.w;
    ar[u][12] = D.x; ar[u][13] = D.y; ar[u][14] = D.z; ar[u][15] = D.w;
  }
  int p[4];
#pragma unroll
  for (int u = 0; u < 4; ++u) p[u] = pos[min(e0 + u, E - 1)];

  // ---- layers 0 and 1 in one d-pass ----
  float s0[4] = {0.f, 0.f, 0.f, 0.f}, s1[4] = {0.f, 0.f, 0.f, 0.f};
  for (int d = 0; d < 64; ++d) {
    const float* w0 = WeT + d * 16;
    const float* w1 = WeT + (64 + d) * 16;
    float p0[4] = {0.f, 0.f, 0.f, 0.f}, p1[4] = {0.f, 0.f, 0.f, 0.f};
#pragma unroll
    for (int k = 0; k < 16; ++k) {
      float wa = w0[k], wb = w1[k];
#pragma unroll
      for (int u = 0; u < 4; ++u) {
        p0[u] = fmaf(ar[u][k], wa, p0[u]);
        p1[u] = fmaf(ar[u][k], wb, p1[u]);
      }
    }
    float a0 = att0[128 + d], a1 = att1[128 + d];
#pragma unroll
    for (int u = 0; u < 4; ++u) {
      s0[u] = fmaf(fmaxf(p0[u], 0.f), a0, s0[u]);
      s1[u] = fmaf(fmaxf(p1[u], 0.f), a1, s1[u]);
    }
  }
#pragma unroll
  for (int u = 0; u < 4; ++u) {
    if (e0 + u < E) { ep0[p[u]] = s0[u]; ep1[p[u]] = s1[u]; }
  }

  // ---- layer 2, head-by-head to cap live registers ----
  float s2[4][4];
  for (int h = 0; h < 4; ++h) {
    float sh[4] = {0.f, 0.f, 0.f, 0.f};
    const float* wh = WeT + (128 + h * 64) * 16;
    const float* ah = att2 + h * 192 + 128;
    for (int d = 0; d < 64; ++d) {
      const float* w = wh + d * 16;
      float pr[4] = {0.f, 0.f, 0.f, 0.f};
#pragma unroll
      for (int k = 0; k < 16; ++k) {
        float wv = w[k];
#pragma unroll
        for (int u = 0; u < 4; ++u) pr[u] = fmaf(ar[u][k], wv, pr[u]);
      }
      float av = ah[d];
#pragma unroll
      for (int u = 0; u < 4; ++u) sh[u] = fmaf(fmaxf(pr[u], 0.f), av, sh[u]);
    }
#pragma unroll
    for (int u = 0; u < 4; ++u) s2[u][h] = sh[u];
  }
#pragma unroll
  for (int u = 0; u < 4; ++u) {
    if (e0 + u < E) {
      float4 v = make_float4(s2[u][0], s2[u][1], s2[u][2], s2[u][3]);
      reinterpret_cast<float4*>(ep2)[p[u]] = v;
    }
  }
}

// ---------------- fused attention softmax + aggregate ----------------

template <int H>
__device__ __forceinline__ void loadH(const float* __restrict__ p, float* v) {
  if constexpr (H == 4) {
    float4 t = *reinterpret_cast<const float4*>(p);
    v[0] = t.x; v[1] = t.y; v[2] = t.z; v[3] = t.w;
  } else {
    v[0] = *p;
  }
}

// one wave per node, all H heads together.
// agg[n, h*F + f] = sum_e alpha_{e,h} * hin[src_e, f]
template <int F, int H>
__global__ __launch_bounds__(256) void k_attn_agg(
    const int* __restrict__ off, const int* __restrict__ ssrc,
    const float* __restrict__ hin, const float* __restrict__ ajd,
    const float* __restrict__ aid, const float* __restrict__ ep,
    float* __restrict__ outbuf, int N) {
  constexpr int FPL = F / 64;
  __shared__ float ls_alpha[4][64 * H];
  __shared__ int ls_src[4][64];
  const int wave = threadIdx.x >> 6, lane = threadIdx.x & 63;
  float* const la = ls_alpha[wave];
  int* const lsrc = ls_src[wave];

  for (int n = blockIdx.x * 4 + wave; n < N; n += gridDim.x * 4) {
    const int o0 = off[n];
    const int deg = off[n + 1] - o0;
    float aidn[H];
    loadH<H>(aid + (size_t)n * H, aidn);

    // ---- pass 1: online softmax stats (lane-parallel over edges) ----
    float m[H], s[H];
#pragma unroll
    for (int h = 0; h < H; ++h) { m[h] = -1e30f; s[h] = 0.f; }
    for (int i = lane; i < deg; i += 64) {
      int sr = ssrc[o0 + i];
      float aj[H], pv[H];
      loadH<H>(ajd + (size_t)sr * H, aj);
      loadH<H>(ep + (size_t)(o0 + i) * H, pv);
#pragma unroll
      for (int h = 0; h < H; ++h) {
        float sc = aj[h] + aidn[h] + pv[h];
        sc = sc > 0.f ? sc : 0.2f * sc;
        float mn = fmaxf(m[h], sc);
        s[h] = s[h] * __expf(m[h] - mn) + __expf(sc - mn);
        m[h] = mn;
      }
    }
#pragma unroll
    for (int o = 32; o > 0; o >>= 1) {
#pragma unroll
      for (int h = 0; h < H; ++h) {
        float m2 = __shfl_xor(m[h], o, 64);
        float s2 = __shfl_xor(s[h], o, 64);
        float mn = fmaxf(m[h], m2);
        s[h] = s[h] * __expf(m[h] - mn) + s2 * __expf(m2 - mn);
        m[h] = mn;
      }
    }
    float inv[H];
#pragma unroll
    for (int h = 0; h < H; ++h) inv[h] = 1.f / (s[h] + 1e-16f);

    // ---- pass 2: chunked alpha -> LDS, then 4-way unrolled gather+FMA ----
    float acc[H][FPL];
#pragma unroll
    for (int h = 0; h < H; ++h)
#pragma unroll
      for (int c = 0; c < FPL; ++c) acc[h][c] = 0.f;

    for (int base = 0; base < deg; base += 64) {
      const int cnt = min(64, deg - base);
      if (lane < cnt) {
        int i = base + lane;
        int sr = ssrc[o0 + i];
        lsrc[lane] = sr;
        float aj[H], pv[H];
        loadH<H>(ajd + (size_t)sr * H, aj);
        loadH<H>(ep + (size_t)(o0 + i) * H, pv);
#pragma unroll
        for (int h = 0; h < H; ++h) {
          float sc = aj[h] + aidn[h] + pv[h];
          sc = sc > 0.f ? sc : 0.2f * sc;
          la[lane * H + h] = __expf(sc - m[h]) * inv[h];
        }
      }
      asm volatile("s_waitcnt lgkmcnt(0)" ::: "memory");

      int j = 0;
      for (; j + 4 <= cnt; j += 4) {
        int srj[4];
        float av[4][H];
#pragma unroll
        for (int u = 0; u < 4; ++u) {
          srj[u] = lsrc[j + u];
          loadH<H>(la + (j + u) * H, av[u]);
        }
        float v[4][FPL];
#pragma unroll
        for (int u = 0; u < 4; ++u) {
          const float* hr = hin + (size_t)srj[u] * F + lane;
#pragma unroll
          for (int c = 0; c < FPL; ++c) v[u][c] = hr[c * 64];
        }
#pragma unroll
        for (int u = 0; u < 4; ++u)
#pragma unroll
          for (int h = 0; h < H; ++h)
#pragma unroll
            for (int c = 0; c < FPL; ++c)
              acc[h][c] = fmaf(av[u][h], v[u][c], acc[h][c]);
      }
      for (; j < cnt; ++j) {
        int sr = lsrc[j];
        float av[H];
        loadH<H>(la + j * H, av);
        const float* hr = hin + (size_t)sr * F + lane;
#pragma unroll
        for (int h = 0; h < H; ++h)
#pragma unroll
          for (int c = 0; c < FPL; ++c)
            acc[h][c] = fmaf(av[h], hr[c * 64], acc[h][c]);
      }
    }

    float* ob = outbuf + (size_t)n * (H * F);
#pragma unroll
    for (int h = 0; h < H; ++h)
#pragma unroll
      for (int c = 0; c < FPL; ++c) ob[h * F + c * 64 + lane] = acc[h][c];
  }
}

// ---------------- post GEMM: out[n, h*64+j] = agg[n,h,:] @ W[:, h*64+j] (+ELU) ----------------
// Weights live in per-thread registers (thread owns output column j).
// Activations ag[n,h,:] are wave-uniform -> scalar loads; no LDS traffic.

template <int F, int H, bool ELU_ACT>
__global__ __launch_bounds__(256) void k_post_reg(const float* __restrict__ agg,
                                                  const float* __restrict__ W,
                                                  float* __restrict__ out, int N) {
  constexpr int CO = H * 64;
  constexpr int NPB = 256 / CO;       // nodes per block-iteration
  const int tid = threadIdx.x;
  const int wave = tid >> 6;
  const int lane = tid & 63;
  const int sub = wave / H;           // node sub-index within block
  const int h = wave % H;
  const int j = h * 64 + lane;        // output column
  float w[F];
#pragma unroll
  for (int k = 0; k < F; ++k) w[k] = W[(size_t)k * CO + j];
  for (int n = blockIdx.x * NPB + sub; n < N; n += gridDim.x * NPB) {
    const float* ag = agg + (size_t)n * (H * F) + (size_t)h * F;
    float a = 0.f;
#pragma unroll
    for (int k = 0; k < F; ++k) a = fmaf(ag[k], w[k], a);
    if (ELU_ACT) a = (a > 0.f) ? a : expm1f(a);
    out[(size_t)n * CO + j] = a;
  }
}

// ---------------- launch ----------------

extern "C" void kernel_launch(void* const* d_in, const int* in_sizes, int n_in,
                              void* d_out, int out_size, void* d_ws, size_t ws_size,
                              hipStream_t stream) {
  const float* x    = (const float*)d_in[0];
  const int*   ei   = (const int*)d_in[1];
  const float* ea   = (const float*)d_in[2];
  const float* W0   = (const float*)d_in[3];
  const float* We0  = (const float*)d_in[4];
  const float* att0 = (const float*)d_in[5];
  const float* W1   = (const float*)d_in[6];
  const float* We1  = (const float*)d_in[7];
  const float* att1 = (const float*)d_in[8];
  const float* W2   = (const float*)d_in[9];
  const float* We2  = (const float*)d_in[10];
  const float* att2 = (const float*)d_in[11];
  float* out = (float*)d_out;

  const int N = in_sizes[0] / 128;   // 50000
  const int E = in_sizes[2] / 16;    // 800000

  char* p = (char*)d_ws;
  auto alloc = [&](size_t bytes) {
    char* r = p;
    p += (bytes + 255) & ~(size_t)255;
    return r;
  };
  int*   flag = (int*)  alloc(sizeof(int));
  int*   off  = (int*)  alloc((size_t)(N + 1) * sizeof(int));
  int*   cur  = (int*)  alloc((size_t)N * sizeof(int));
  int*   pos  = (int*)  alloc((size_t)E * sizeof(int));
  int*   ssrc = (int*)  alloc((size_t)E * sizeof(int));
  float* WeT  = (float*)alloc(384 * 16 * sizeof(float));
  float* waj0 = (float*)alloc(128 * sizeof(float));
  float* wai0 = (float*)alloc(128 * sizeof(float));
  float* waj1 = (float*)alloc(64 * sizeof(float));
  float* wai1 = (float*)alloc(64 * sizeof(float));
  float* waj2 = (float*)alloc(256 * sizeof(float));
  float* wai2 = (float*)alloc(256 * sizeof(float));
  float* ajd  = (float*)alloc((size_t)N * 4 * sizeof(float));
  float* aid  = (float*)alloc((size_t)N * 4 * sizeof(float));
  float* ep0  = (float*)alloc((size_t)E * sizeof(float));
  float* ep1  = (float*)alloc((size_t)E * sizeof(float));
  float* ep2  = (float*)alloc((size_t)E * 4 * sizeof(float));
  float* hbuf = (float*)alloc((size_t)N * 64 * sizeof(float));
  float* agg  = (float*)alloc((size_t)N * 256 * sizeof(float));

  const int eb = (E + THR - 1) / THR;
  const int eb4 = ((E + 3) / 4 + THR - 1) / THR;
  const int nb = (N + THR - 1) / THR;
  const int ab = (N + 3) / 4;

  hipMemsetAsync(flag, 0, sizeof(int), stream);
  hipMemsetAsync(cur, 0, (size_t)N * sizeof(int), stream);

  k_detect<<<16, THR, 0, stream>>>(ei, flag);
  k_count<<<eb, THR, 0, stream>>>(ei, flag, cur, E);
  k_scan<<<1, 1024, 0, stream>>>(cur, off, N);
  k_scatter<<<eb, THR, 0, stream>>>(ei, flag, cur, pos, ssrc, E);

  k_transpose_we<<<24, THR, 0, stream>>>(We0, We1, We2, WeT);
  k_fold_att<<<1, 128, 0, stream>>>(W0, att0, waj0, wai0, 128, 1);
  k_fold_att<<<1, 64, 0, stream>>>(W1, att1, waj1, wai1, 64, 1);
  k_fold_att<<<1, 256, 0, stream>>>(W2, att2, waj2, wai2, 64, 4);
  k_ep<<<eb4, THR, 0, stream>>>(ea, WeT, att0, att1, att2, pos, ep0, ep1, ep2, E);

  // layer 0: Cin=128, H=1
  k_node_dots<128, 1><<<nb, THR, 0, stream>>>(x, waj0, wai0, ajd, aid, N);
  k_attn_agg<128, 1><<<ab, THR, 0, stream>>>(off, ssrc, x, ajd, aid, ep0, agg, N);
  k_post_reg<128, 1, true><<<1024, THR, 0, stream>>>(agg, W0, hbuf, N);

  // layer 1: Cin=64, H=1
  k_node_dots<64, 1><<<nb, THR, 0, stream>>>(hbuf, waj1, wai1, ajd, aid, N);
  k_attn_agg<64, 1><<<ab, THR, 0, stream>>>(off, ssrc, hbuf, ajd, aid, ep1, agg, N);
  k_post_reg<64, 1, true><<<1024, THR, 0, stream>>>(agg, W1, hbuf, N);

  // layer 2: Cin=64, H=4 (all heads in one wave)
  k_node_dots<64, 4><<<nb, THR, 0, stream>>>(hbuf, waj2, wai2, ajd, aid, N);
  k_attn_agg<64, 4><<<ab, THR, 0, stream>>>(off, ssrc, hbuf, ajd, aid, ep2, agg, N);
  k_post_reg<64, 4, false><<<1024, THR, 0, stream>>>(agg, W2, out, N);
}

// Round 7
// 784.855 us; speedup vs baseline: 1.0831x; 1.0831x over previous
//
#include <hip/hip_runtime.h>
#include <math.h>

#define THR 256

// ---------------- CSR build ----------------

// Detect whether edge_index buffer is int64 (high words all zero) or int32.
__global__ void k_detect(const int* __restrict__ w, int* __restrict__ flag) {
  int i = blockIdx.x * blockDim.x + threadIdx.x;
  if (i < 4096) {
    if (w[2 * i + 1] != 0) atomicOr(flag, 1);
  }
}

__device__ __forceinline__ int load_idx(const int* __restrict__ w, int pos, int is32) {
  return is32 ? w[pos] : w[2 * pos];
}

__global__ void k_count(const int* __restrict__ ei, const int* __restrict__ flag,
                        int* __restrict__ cnt, int E) {
  int e = blockIdx.x * blockDim.x + threadIdx.x;
  if (e < E) {
    int is32 = *flag;
    int d = load_idx(ei, E + e, is32);
    atomicAdd(&cnt[d], 1);
  }
}

__global__ __launch_bounds__(1024) void k_scan(int* __restrict__ cnt_cur, int* __restrict__ off, int n) {
  __shared__ int part[1024];
  int tid = threadIdx.x;
  int chunk = (n + 1023) / 1024;
  int s0 = tid * chunk;
  int s1 = min(s0 + chunk, n);
  int s = 0;
  for (int i = s0; i < s1; ++i) s += cnt_cur[i];
  part[tid] = s;
  __syncthreads();
  for (int d = 1; d < 1024; d <<= 1) {
    int v = (tid >= d) ? part[tid - d] : 0;
    __syncthreads();
    part[tid] += v;
    __syncthreads();
  }
  int excl = (tid == 0) ? 0 : part[tid - 1];
  for (int i = s0; i < s1; ++i) {
    int c = cnt_cur[i];
    off[i] = excl;
    cnt_cur[i] = excl;   // cursor copy for scatter
    excl += c;
  }
  if (tid == 1023) off[n] = part[1023];
}

__global__ void k_scatter(const int* __restrict__ ei, const int* __restrict__ flag,
                          int* __restrict__ cur, int* __restrict__ pos,
                          int* __restrict__ ssrc, int E) {
  int e = blockIdx.x * blockDim.x + threadIdx.x;
  if (e < E) {
    int is32 = *flag;
    int d = load_idx(ei, E + e, is32);
    int s = load_idx(ei, e, is32);
    int p = atomicAdd(&cur[d], 1);
    pos[e] = p;
    ssrc[p] = s;
  }
}

// ---------------- weight prep ----------------

// WeT rows: layer0 d=0..63 ; layer1 rows 64..127 ; layer2 rows 128..383
__global__ void k_transpose_we(const float* __restrict__ We0, const float* __restrict__ We1,
                               const float* __restrict__ We2, float* __restrict__ WeT) {
  int i = blockIdx.x * blockDim.x + threadIdx.x;
  if (i >= 384 * 16) return;
  int row = i >> 4, k = i & 15;
  float v;
  if (row < 64)        v = We0[k * 64 + row];
  else if (row < 128)  v = We1[k * 64 + (row - 64)];
  else                 v = We2[k * 256 + (row - 128)];
  WeT[i] = v;
}

__global__ void k_fold_att(const float* __restrict__ W, const float* __restrict__ att,
                           float* __restrict__ waj, float* __restrict__ wai,
                           int Cin, int H) {
  int i = blockIdx.x * blockDim.x + threadIdx.x;
  if (i >= Cin * H) return;
  int k = i / H, h = i % H;
  float sj = 0.f, si = 0.f;
  for (int d = 0; d < 64; ++d) {
    float w = W[k * (H * 64) + h * 64 + d];
    sj = fmaf(w, att[h * 192 + d], sj);
    si = fmaf(w, att[h * 192 + 64 + d], si);
  }
  waj[k * H + h] = sj;
  wai[k * H + h] = si;
}

template <int CIN, int H>
__global__ void k_node_dots(const float* __restrict__ xin, const float* __restrict__ waj,
                            const float* __restrict__ wai, float* __restrict__ ajd,
                            float* __restrict__ aid, int N) {
  int n = blockIdx.x * blockDim.x + threadIdx.x;
  if (n >= N) return;
  float sj[H], si[H];
#pragma unroll
  for (int h = 0; h < H; ++h) { sj[h] = 0.f; si[h] = 0.f; }
  const float* xr = xin + (size_t)n * CIN;
#pragma unroll 4
  for (int k = 0; k < CIN; ++k) {
    float xv = xr[k];
#pragma unroll
    for (int h = 0; h < H; ++h) {
      sj[h] = fmaf(xv, waj[k * H + h], sj[h]);
      si[h] = fmaf(xv, wai[k * H + h], si[h]);
    }
  }
#pragma unroll
  for (int h = 0; h < H; ++h) {
    ajd[(size_t)n * H + h] = sj[h];
    aid[(size_t)n * H + h] = si[h];
  }
}

// ---------------- edge scalar ep (1 edge/thread, regs pinned, CSR-sorted writes) ----------------

// By-value float4 dot: keeps operands in VGPRs (no addressable array -> no scratch).
__device__ __forceinline__ float dot4(float4 a, float4 w, float acc) {
  acc = fmaf(a.x, w.x, acc);
  acc = fmaf(a.y, w.y, acc);
  acc = fmaf(a.z, w.z, acc);
  acc = fmaf(a.w, w.w, acc);
  return acc;
}

// ep[e,h] = sum_d relu(ea[e]·We[:,d]) * a_p[h,d] for all 3 layers.
__global__ __launch_bounds__(256, 8) void k_ep(
    const float* __restrict__ ea, const float* __restrict__ WeT,
    const float* __restrict__ att0, const float* __restrict__ att1,
    const float* __restrict__ att2, const int* __restrict__ pos,
    float* __restrict__ ep0, float* __restrict__ ep1,
    float* __restrict__ ep2, int E) {
  const int e = blockIdx.x * blockDim.x + threadIdx.x;
  if (e >= E) return;
  const float4* eav = reinterpret_cast<const float4*>(ea + (size_t)e * 16);
  const float4 A0 = eav[0], A1 = eav[1], A2 = eav[2], A3 = eav[3];
  const int p = pos[e];
  const float4* wt = reinterpret_cast<const float4*>(WeT);

  // ---- layers 0 and 1 in one d-pass ----
  float s0 = 0.f, s1 = 0.f;
  for (int d = 0; d < 64; ++d) {
    float4 W0 = wt[d * 4 + 0], W1 = wt[d * 4 + 1], W2 = wt[d * 4 + 2], W3 = wt[d * 4 + 3];
    float4 V0 = wt[(64 + d) * 4 + 0], V1 = wt[(64 + d) * 4 + 1],
           V2 = wt[(64 + d) * 4 + 2], V3 = wt[(64 + d) * 4 + 3];
    float p0 = dot4(A3, W3, dot4(A2, W2, dot4(A1, W1, dot4(A0, W0, 0.f))));
    float p1 = dot4(A3, V3, dot4(A2, V2, dot4(A1, V1, dot4(A0, V0, 0.f))));
    s0 = fmaf(fmaxf(p0, 0.f), att0[128 + d], s0);
    s1 = fmaf(fmaxf(p1, 0.f), att1[128 + d], s1);
  }
  ep0[p] = s0;
  ep1[p] = s1;

  // ---- layer 2, 4 heads ----
  float4 s2 = make_float4(0.f, 0.f, 0.f, 0.f);
#pragma unroll
  for (int h = 0; h < 4; ++h) {
    float sh = 0.f;
    const float4* wh = wt + (size_t)(128 + h * 64) * 4;
    const float* ah = att2 + h * 192 + 128;
    for (int d = 0; d < 64; ++d) {
      float4 W0 = wh[d * 4 + 0], W1 = wh[d * 4 + 1], W2 = wh[d * 4 + 2], W3 = wh[d * 4 + 3];
      float pr = dot4(A3, W3, dot4(A2, W2, dot4(A1, W1, dot4(A0, W0, 0.f))));
      sh = fmaf(fmaxf(pr, 0.f), ah[d], sh);
    }
    if (h == 0) s2.x = sh;
    else if (h == 1) s2.y = sh;
    else if (h == 2) s2.z = sh;
    else s2.w = sh;
  }
  reinterpret_cast<float4*>(ep2)[p] = s2;
}

// ---------------- fused attention softmax + aggregate ----------------

template <int H>
__device__ __forceinline__ void loadH(const float* __restrict__ p, float* v) {
  if constexpr (H == 4) {
    float4 t = *reinterpret_cast<const float4*>(p);
    v[0] = t.x; v[1] = t.y; v[2] = t.z; v[3] = t.w;
  } else {
    v[0] = *p;
  }
}

// one wave per node, all H heads together.
// agg[n, h*F + f] = sum_e alpha_{e,h} * hin[src_e, f]
template <int F, int H>
__global__ __launch_bounds__(256) void k_attn_agg(
    const int* __restrict__ off, const int* __restrict__ ssrc,
    const float* __restrict__ hin, const float* __restrict__ ajd,
    const float* __restrict__ aid, const float* __restrict__ ep,
    float* __restrict__ outbuf, int N) {
  constexpr int FPL = F / 64;
  __shared__ float ls_alpha[4][64 * H];
  __shared__ int ls_src[4][64];
  const int wave = threadIdx.x >> 6, lane = threadIdx.x & 63;
  float* const la = ls_alpha[wave];
  int* const lsrc = ls_src[wave];

  for (int n = blockIdx.x * 4 + wave; n < N; n += gridDim.x * 4) {
    const int o0 = off[n];
    const int deg = off[n + 1] - o0;
    float aidn[H];
    loadH<H>(aid + (size_t)n * H, aidn);

    // ---- pass 1: online softmax stats (lane-parallel over edges) ----
    float m[H], s[H];
#pragma unroll
    for (int h = 0; h < H; ++h) { m[h] = -1e30f; s[h] = 0.f; }
    for (int i = lane; i < deg; i += 64) {
      int sr = ssrc[o0 + i];
      float aj[H], pv[H];
      loadH<H>(ajd + (size_t)sr * H, aj);
      loadH<H>(ep + (size_t)(o0 + i) * H, pv);
#pragma unroll
      for (int h = 0; h < H; ++h) {
        float sc = aj[h] + aidn[h] + pv[h];
        sc = sc > 0.f ? sc : 0.2f * sc;
        float mn = fmaxf(m[h], sc);
        s[h] = s[h] * __expf(m[h] - mn) + __expf(sc - mn);
        m[h] = mn;
      }
    }
#pragma unroll
    for (int o = 32; o > 0; o >>= 1) {
#pragma unroll
      for (int h = 0; h < H; ++h) {
        float m2 = __shfl_xor(m[h], o, 64);
        float s2 = __shfl_xor(s[h], o, 64);
        float mn = fmaxf(m[h], m2);
        s[h] = s[h] * __expf(m[h] - mn) + s2 * __expf(m2 - mn);
        m[h] = mn;
      }
    }
    float inv[H];
#pragma unroll
    for (int h = 0; h < H; ++h) inv[h] = 1.f / (s[h] + 1e-16f);

    // ---- pass 2: chunked alpha -> LDS, then 4-way unrolled gather+FMA ----
    float acc[H][FPL];
#pragma unroll
    for (int h = 0; h < H; ++h)
#pragma unroll
      for (int c = 0; c < FPL; ++c) acc[h][c] = 0.f;

    for (int base = 0; base < deg; base += 64) {
      const int cnt = min(64, deg - base);
      if (lane < cnt) {
        int i = base + lane;
        int sr = ssrc[o0 + i];
        lsrc[lane] = sr;
        float aj[H], pv[H];
        loadH<H>(ajd + (size_t)sr * H, aj);
        loadH<H>(ep + (size_t)(o0 + i) * H, pv);
#pragma unroll
        for (int h = 0; h < H; ++h) {
          float sc = aj[h] + aidn[h] + pv[h];
          sc = sc > 0.f ? sc : 0.2f * sc;
          la[lane * H + h] = __expf(sc - m[h]) * inv[h];
        }
      }
      asm volatile("s_waitcnt lgkmcnt(0)" ::: "memory");

      int j = 0;
      for (; j + 4 <= cnt; j += 4) {
        int srj[4];
        float av[4][H];
#pragma unroll
        for (int u = 0; u < 4; ++u) {
          srj[u] = lsrc[j + u];
          loadH<H>(la + (j + u) * H, av[u]);
        }
        float v[4][FPL];
#pragma unroll
        for (int u = 0; u < 4; ++u) {
          const float* hr = hin + (size_t)srj[u] * F + lane;
#pragma unroll
          for (int c = 0; c < FPL; ++c) v[u][c] = hr[c * 64];
        }
#pragma unroll
        for (int u = 0; u < 4; ++u)
#pragma unroll
          for (int h = 0; h < H; ++h)
#pragma unroll
            for (int c = 0; c < FPL; ++c)
              acc[h][c] = fmaf(av[u][h], v[u][c], acc[h][c]);
      }
      for (; j < cnt; ++j) {
        int sr = lsrc[j];
        float av[H];
        loadH<H>(la + j * H, av);
        const float* hr = hin + (size_t)sr * F + lane;
#pragma unroll
        for (int h = 0; h < H; ++h)
#pragma unroll
          for (int c = 0; c < FPL; ++c)
            acc[h][c] = fmaf(av[h], hr[c * 64], acc[h][c]);
      }
    }

    float* ob = outbuf + (size_t)n * (H * F);
#pragma unroll
    for (int h = 0; h < H; ++h)
#pragma unroll
      for (int c = 0; c < FPL; ++c) ob[h * F + c * 64 + lane] = acc[h][c];
  }
}

// ---------------- post GEMM: out[n, h*64+j] = agg[n,h,:] @ W[:, h*64+j] (+ELU) ----------------
// Weights live in per-thread registers (thread owns output column j).
// Activations ag[n,h,:] are wave-uniform -> scalar loads; no LDS traffic.

template <int F, int H, bool ELU_ACT>
__global__ __launch_bounds__(256) void k_post_reg(const float* __restrict__ agg,
                                                  const float* __restrict__ W,
                                                  float* __restrict__ out, int N) {
  constexpr int CO = H * 64;
  constexpr int NPB = 256 / CO;       // nodes per block-iteration
  const int tid = threadIdx.x;
  const int wave = tid >> 6;
  const int lane = tid & 63;
  const int sub = wave / H;           // node sub-index within block
  const int h = wave % H;
  const int j = h * 64 + lane;        // output column
  float w[F];
#pragma unroll
  for (int k = 0; k < F; ++k) w[k] = W[(size_t)k * CO + j];
  for (int n = blockIdx.x * NPB + sub; n < N; n += gridDim.x * NPB) {
    const float* ag = agg + (size_t)n * (H * F) + (size_t)h * F;
    float a = 0.f;
#pragma unroll
    for (int k = 0; k < F; ++k) a = fmaf(ag[k], w[k], a);
    if (ELU_ACT) a = (a > 0.f) ? a : expm1f(a);
    out[(size_t)n * CO + j] = a;
  }
}

// ---------------- launch ----------------

extern "C" void kernel_launch(void* const* d_in, const int* in_sizes, int n_in,
                              void* d_out, int out_size, void* d_ws, size_t ws_size,
                              hipStream_t stream) {
  const float* x    = (const float*)d_in[0];
  const int*   ei   = (const int*)d_in[1];
  const float* ea   = (const float*)d_in[2];
  const float* W0   = (const float*)d_in[3];
  const float* We0  = (const float*)d_in[4];
  const float* att0 = (const float*)d_in[5];
  const float* W1   = (const float*)d_in[6];
  const float* We1  = (const float*)d_in[7];
  const float* att1 = (const float*)d_in[8];
  const float* W2   = (const float*)d_in[9];
  const float* We2  = (const float*)d_in[10];
  const float* att2 = (const float*)d_in[11];
  float* out = (float*)d_out;

  const int N = in_sizes[0] / 128;   // 50000
  const int E = in_sizes[2] / 16;    // 800000

  char* p = (char*)d_ws;
  auto alloc = [&](size_t bytes) {
    char* r = p;
    p += (bytes + 255) & ~(size_t)255;
    return r;
  };
  int*   flag = (int*)  alloc(sizeof(int));
  int*   off  = (int*)  alloc((size_t)(N + 1) * sizeof(int));
  int*   cur  = (int*)  alloc((size_t)N * sizeof(int));
  int*   pos  = (int*)  alloc((size_t)E * sizeof(int));
  int*   ssrc = (int*)  alloc((size_t)E * sizeof(int));
  float* WeT  = (float*)alloc(384 * 16 * sizeof(float));
  float* waj0 = (float*)alloc(128 * sizeof(float));
  float* wai0 = (float*)alloc(128 * sizeof(float));
  float* waj1 = (float*)alloc(64 * sizeof(float));
  float* wai1 = (float*)alloc(64 * sizeof(float));
  float* waj2 = (float*)alloc(256 * sizeof(float));
  float* wai2 = (float*)alloc(256 * sizeof(float));
  float* ajd  = (float*)alloc((size_t)N * 4 * sizeof(float));
  float* aid  = (float*)alloc((size_t)N * 4 * sizeof(float));
  float* ep0  = (float*)alloc((size_t)E * sizeof(float));
  float* ep1  = (float*)alloc((size_t)E * sizeof(float));
  float* ep2  = (float*)alloc((size_t)E * 4 * sizeof(float));
  float* hbuf = (float*)alloc((size_t)N * 64 * sizeof(float));
  float* agg  = (float*)alloc((size_t)N * 256 * sizeof(float));

  const int eb = (E + THR - 1) / THR;
  const int nb = (N + THR - 1) / THR;
  const int ab = (N + 3) / 4;

  hipMemsetAsync(flag, 0, sizeof(int), stream);
  hipMemsetAsync(cur, 0, (size_t)N * sizeof(int), stream);

  k_detect<<<16, THR, 0, stream>>>(ei, flag);
  k_count<<<eb, THR, 0, stream>>>(ei, flag, cur, E);
  k_scan<<<1, 1024, 0, stream>>>(cur, off, N);
  k_scatter<<<eb, THR, 0, stream>>>(ei, flag, cur, pos, ssrc, E);

  k_transpose_we<<<24, THR, 0, stream>>>(We0, We1, We2, WeT);
  k_fold_att<<<1, 128, 0, stream>>>(W0, att0, waj0, wai0, 128, 1);
  k_fold_att<<<1, 64, 0, stream>>>(W1, att1, waj1, wai1, 64, 1);
  k_fold_att<<<1, 256, 0, stream>>>(W2, att2, waj2, wai2, 64, 4);
  k_ep<<<eb, THR, 0, stream>>>(ea, WeT, att0, att1, att2, pos, ep0, ep1, ep2, E);

  // layer 0: Cin=128, H=1
  k_node_dots<128, 1><<<nb, THR, 0, stream>>>(x, waj0, wai0, ajd, aid, N);
  k_attn_agg<128, 1><<<ab, THR, 0, stream>>>(off, ssrc, x, ajd, aid, ep0, agg, N);
  k_post_reg<128, 1, true><<<1024, THR, 0, stream>>>(agg, W0, hbuf, N);

  // layer 1: Cin=64, H=1
  k_node_dots<64, 1><<<nb, THR, 0, stream>>>(hbuf, waj1, wai1, ajd, aid, N);
  k_attn_agg<64, 1><<<ab, THR, 0, stream>>>(off, ssrc, hbuf, ajd, aid, ep1, agg, N);
  k_post_reg<64, 1, true><<<1024, THR, 0, stream>>>(agg, W1, hbuf, N);

  // layer 2: Cin=64, H=4 (all heads in one wave)
  k_node_dots<64, 4><<<nb, THR, 0, stream>>>(hbuf, waj2, wai2, ajd, aid, N);
  k_attn_agg<64, 4><<<ab, THR, 0, stream>>>(off, ssrc, hbuf, ajd, aid, ep2, agg, N);
  k_post_reg<64, 4, false><<<1024, THR, 0, stream>>>(agg, W2, out, N);
}

// Round 8
// 775.100 us; speedup vs baseline: 1.0968x; 1.0126x over previous
//
#include <hip/hip_runtime.h>
#include <math.h>

#define THR 256

// ---------------- CSR build ----------------

// Detect whether edge_index buffer is int64 (high words all zero) or int32.
__global__ void k_detect(const int* __restrict__ w, int* __restrict__ flag) {
  int i = blockIdx.x * blockDim.x + threadIdx.x;
  if (i < 4096) {
    if (w[2 * i + 1] != 0) atomicOr(flag, 1);
  }
}

__device__ __forceinline__ int load_idx(const int* __restrict__ w, int pos, int is32) {
  return is32 ? w[pos] : w[2 * pos];
}

__global__ void k_count(const int* __restrict__ ei, const int* __restrict__ flag,
                        int* __restrict__ cnt, int E) {
  int e = blockIdx.x * blockDim.x + threadIdx.x;
  if (e < E) {
    int is32 = *flag;
    int d = load_idx(ei, E + e, is32);
    atomicAdd(&cnt[d], 1);
  }
}

__global__ __launch_bounds__(1024) void k_scan(int* __restrict__ cnt_cur, int* __restrict__ off, int n) {
  __shared__ int part[1024];
  int tid = threadIdx.x;
  int chunk = (n + 1023) / 1024;
  int s0 = tid * chunk;
  int s1 = min(s0 + chunk, n);
  int s = 0;
  for (int i = s0; i < s1; ++i) s += cnt_cur[i];
  part[tid] = s;
  __syncthreads();
  for (int d = 1; d < 1024; d <<= 1) {
    int v = (tid >= d) ? part[tid - d] : 0;
    __syncthreads();
    part[tid] += v;
    __syncthreads();
  }
  int excl = (tid == 0) ? 0 : part[tid - 1];
  for (int i = s0; i < s1; ++i) {
    int c = cnt_cur[i];
    off[i] = excl;
    cnt_cur[i] = excl;   // cursor copy for scatter
    excl += c;
  }
  if (tid == 1023) off[n] = part[1023];
}

__global__ void k_scatter(const int* __restrict__ ei, const int* __restrict__ flag,
                          int* __restrict__ cur, int* __restrict__ pos,
                          int* __restrict__ ssrc, int E) {
  int e = blockIdx.x * blockDim.x + threadIdx.x;
  if (e < E) {
    int is32 = *flag;
    int d = load_idx(ei, E + e, is32);
    int s = load_idx(ei, e, is32);
    int p = atomicAdd(&cur[d], 1);
    pos[e] = p;
    ssrc[p] = s;
  }
}

// ---------------- weight prep ----------------

__global__ void k_fold_att(const float* __restrict__ W, const float* __restrict__ att,
                           float* __restrict__ waj, float* __restrict__ wai,
                           int Cin, int H) {
  int i = blockIdx.x * blockDim.x + threadIdx.x;
  if (i >= Cin * H) return;
  int k = i / H, h = i % H;
  float sj = 0.f, si = 0.f;
  for (int d = 0; d < 64; ++d) {
    float w = W[k * (H * 64) + h * 64 + d];
    sj = fmaf(w, att[h * 192 + d], sj);
    si = fmaf(w, att[h * 192 + 64 + d], si);
  }
  waj[k * H + h] = sj;
  wai[k * H + h] = si;
}

template <int CIN, int H>
__global__ void k_node_dots(const float* __restrict__ xin, const float* __restrict__ waj,
                            const float* __restrict__ wai, float* __restrict__ ajd,
                            float* __restrict__ aid, int N) {
  int n = blockIdx.x * blockDim.x + threadIdx.x;
  if (n >= N) return;
  float sj[H], si[H];
#pragma unroll
  for (int h = 0; h < H; ++h) { sj[h] = 0.f; si[h] = 0.f; }
  const float* xr = xin + (size_t)n * CIN;
#pragma unroll 4
  for (int k = 0; k < CIN; ++k) {
    float xv = xr[k];
#pragma unroll
    for (int h = 0; h < H; ++h) {
      sj[h] = fmaf(xv, waj[k * H + h], sj[h]);
      si[h] = fmaf(xv, wai[k * H + h], si[h]);
    }
  }
#pragma unroll
  for (int h = 0; h < H; ++h) {
    ajd[(size_t)n * H + h] = sj[h];
    aid[(size_t)n * H + h] = si[h];
  }
}

// ---------------- edge scalar ep: LDS-staged edge rows, SGPR weights ----------------

// One unit: s = sum_{d=0..63} relu( sum_k sm[k][t] * W[k*STRIDE + d] ) * a[d]
// dblk loop rolled (8 d per iter); k fully unrolled; acc indices all compile-time.
// Edge value from LDS (per-lane ds_read_b32, conflict-free); weight + att values
// are wave-uniform -> scalar loads; FMA takes the SGPR operand directly.
template <int STRIDE>
__device__ __forceinline__ float ep_unit(const float* __restrict__ sm, int t,
                                         const float* __restrict__ W,
                                         const float* __restrict__ a) {
  float s = 0.f;
  for (int db = 0; db < 8; ++db) {
    float acc[8] = {0.f, 0.f, 0.f, 0.f, 0.f, 0.f, 0.f, 0.f};
    const float* wb = W + db * 8;
#pragma unroll
    for (int k = 0; k < 16; ++k) {
      float av = sm[k * 256 + t];
      const float* w = wb + k * STRIDE;
#pragma unroll
      for (int j = 0; j < 8; ++j) acc[j] = fmaf(av, w[j], acc[j]);
    }
    const float* ad = a + db * 8;
#pragma unroll
    for (int j = 0; j < 8; ++j) s = fmaf(fmaxf(acc[j], 0.f), ad[j], s);
  }
  return s;
}

__global__ __launch_bounds__(256) void k_ep(
    const float* __restrict__ ea,
    const float* __restrict__ We0, const float* __restrict__ We1,
    const float* __restrict__ We2,
    const float* __restrict__ att0, const float* __restrict__ att1,
    const float* __restrict__ att2, const int* __restrict__ pos,
    float* __restrict__ ep0, float* __restrict__ ep1,
    float* __restrict__ ep2, int E) {
  __shared__ float sm[16 * 256];
  const int t = threadIdx.x;
  const int e = blockIdx.x * 256 + t;
  const int ec = min(e, E - 1);   // clamp so all threads reach barrier; stores guarded

  const float4* eav = reinterpret_cast<const float4*>(ea + (size_t)ec * 16);
  float4 a0 = eav[0], a1 = eav[1], a2 = eav[2], a3 = eav[3];
  sm[0 * 256 + t] = a0.x;  sm[1 * 256 + t] = a0.y;
  sm[2 * 256 + t] = a0.z;  sm[3 * 256 + t] = a0.w;
  sm[4 * 256 + t] = a1.x;  sm[5 * 256 + t] = a1.y;
  sm[6 * 256 + t] = a1.z;  sm[7 * 256 + t] = a1.w;
  sm[8 * 256 + t] = a2.x;  sm[9 * 256 + t] = a2.y;
  sm[10 * 256 + t] = a2.z; sm[11 * 256 + t] = a2.w;
  sm[12 * 256 + t] = a3.x; sm[13 * 256 + t] = a3.y;
  sm[14 * 256 + t] = a3.z; sm[15 * 256 + t] = a3.w;
  const int p = pos[ec];
  __syncthreads();

  float s0 = ep_unit<64>(sm, t, We0, att0 + 128);
  float s1 = ep_unit<64>(sm, t, We1, att1 + 128);
  if (e < E) { ep0[p] = s0; ep1[p] = s1; }

  float4 s2;
  s2.x = ep_unit<256>(sm, t, We2 + 0,   att2 + 0 * 192 + 128);
  s2.y = ep_unit<256>(sm, t, We2 + 64,  att2 + 1 * 192 + 128);
  s2.z = ep_unit<256>(sm, t, We2 + 128, att2 + 2 * 192 + 128);
  s2.w = ep_unit<256>(sm, t, We2 + 192, att2 + 3 * 192 + 128);
  if (e < E) reinterpret_cast<float4*>(ep2)[p] = s2;
}

// ---------------- fused attention softmax + aggregate ----------------

template <int H>
__device__ __forceinline__ void loadH(const float* __restrict__ p, float* v) {
  if constexpr (H == 4) {
    float4 t = *reinterpret_cast<const float4*>(p);
    v[0] = t.x; v[1] = t.y; v[2] = t.z; v[3] = t.w;
  } else {
    v[0] = *p;
  }
}

// one wave per node, all H heads together.
// agg[n, h*F + f] = sum_e alpha_{e,h} * hin[src_e, f]
template <int F, int H>
__global__ __launch_bounds__(256) void k_attn_agg(
    const int* __restrict__ off, const int* __restrict__ ssrc,
    const float* __restrict__ hin, const float* __restrict__ ajd,
    const float* __restrict__ aid, const float* __restrict__ ep,
    float* __restrict__ outbuf, int N) {
  constexpr int FPL = F / 64;
  __shared__ float ls_alpha[4][64 * H];
  __shared__ int ls_src[4][64];
  const int wave = threadIdx.x >> 6, lane = threadIdx.x & 63;
  float* const la = ls_alpha[wave];
  int* const lsrc = ls_src[wave];

  for (int n = blockIdx.x * 4 + wave; n < N; n += gridDim.x * 4) {
    const int o0 = off[n];
    const int deg = off[n + 1] - o0;
    float aidn[H];
    loadH<H>(aid + (size_t)n * H, aidn);

    // ---- pass 1: online softmax stats (lane-parallel over edges) ----
    float m[H], s[H];
#pragma unroll
    for (int h = 0; h < H; ++h) { m[h] = -1e30f; s[h] = 0.f; }
    for (int i = lane; i < deg; i += 64) {
      int sr = ssrc[o0 + i];
      float aj[H], pv[H];
      loadH<H>(ajd + (size_t)sr * H, aj);
      loadH<H>(ep + (size_t)(o0 + i) * H, pv);
#pragma unroll
      for (int h = 0; h < H; ++h) {
        float sc = aj[h] + aidn[h] + pv[h];
        sc = sc > 0.f ? sc : 0.2f * sc;
        float mn = fmaxf(m[h], sc);
        s[h] = s[h] * __expf(m[h] - mn) + __expf(sc - mn);
        m[h] = mn;
      }
    }
#pragma unroll
    for (int o = 32; o > 0; o >>= 1) {
#pragma unroll
      for (int h = 0; h < H; ++h) {
        float m2 = __shfl_xor(m[h], o, 64);
        float s2 = __shfl_xor(s[h], o, 64);
        float mn = fmaxf(m[h], m2);
        s[h] = s[h] * __expf(m[h] - mn) + s2 * __expf(m2 - mn);
        m[h] = mn;
      }
    }
    float inv[H];
#pragma unroll
    for (int h = 0; h < H; ++h) inv[h] = 1.f / (s[h] + 1e-16f);

    // ---- pass 2: chunked alpha -> LDS, then 4-way unrolled gather+FMA ----
    float acc[H][FPL];
#pragma unroll
    for (int h = 0; h < H; ++h)
#pragma unroll
      for (int c = 0; c < FPL; ++c) acc[h][c] = 0.f;

    for (int base = 0; base < deg; base += 64) {
      const int cnt = min(64, deg - base);
      if (lane < cnt) {
        int i = base + lane;
        int sr = ssrc[o0 + i];
        lsrc[lane] = sr;
        float aj[H], pv[H];
        loadH<H>(ajd + (size_t)sr * H, aj);
        loadH<H>(ep + (size_t)(o0 + i) * H, pv);
#pragma unroll
        for (int h = 0; h < H; ++h) {
          float sc = aj[h] + aidn[h] + pv[h];
          sc = sc > 0.f ? sc : 0.2f * sc;
          la[lane * H + h] = __expf(sc - m[h]) * inv[h];
        }
      }
      asm volatile("s_waitcnt lgkmcnt(0)" ::: "memory");

      int j = 0;
      for (; j + 4 <= cnt; j += 4) {
        int srj[4];
        float av[4][H];
#pragma unroll
        for (int u = 0; u < 4; ++u) {
          srj[u] = lsrc[j + u];
          loadH<H>(la + (j + u) * H, av[u]);
        }
        float v[4][FPL];
#pragma unroll
        for (int u = 0; u < 4; ++u) {
          const float* hr = hin + (size_t)srj[u] * F + lane;
#pragma unroll
          for (int c = 0; c < FPL; ++c) v[u][c] = hr[c * 64];
        }
#pragma unroll
        for (int u = 0; u < 4; ++u)
#pragma unroll
          for (int h = 0; h < H; ++h)
#pragma unroll
            for (int c = 0; c < FPL; ++c)
              acc[h][c] = fmaf(av[u][h], v[u][c], acc[h][c]);
      }
      for (; j < cnt; ++j) {
        int sr = lsrc[j];
        float av[H];
        loadH<H>(la + j * H, av);
        const float* hr = hin + (size_t)sr * F + lane;
#pragma unroll
        for (int h = 0; h < H; ++h)
#pragma unroll
          for (int c = 0; c < FPL; ++c)
            acc[h][c] = fmaf(av[h], hr[c * 64], acc[h][c]);
      }
    }

    float* ob = outbuf + (size_t)n * (H * F);
#pragma unroll
    for (int h = 0; h < H; ++h)
#pragma unroll
      for (int c = 0; c < FPL; ++c) ob[h * F + c * 64 + lane] = acc[h][c];
  }
}

// ---------------- post GEMM: out[n, h*64+j] = agg[n,h,:] @ W[:, h*64+j] (+ELU) ----------------
// Weights live in per-thread registers (thread owns output column j).
// Activations ag[n,h,:] are wave-uniform -> scalar loads; no LDS traffic.

template <int F, int H, bool ELU_ACT>
__global__ __launch_bounds__(256) void k_post_reg(const float* __restrict__ agg,
                                                  const float* __restrict__ W,
                                                  float* __restrict__ out, int N) {
  constexpr int CO = H * 64;
  constexpr int NPB = 256 / CO;       // nodes per block-iteration
  const int tid = threadIdx.x;
  const int wave = tid >> 6;
  const int lane = tid & 63;
  const int sub = wave / H;           // node sub-index within block
  const int h = wave % H;
  const int j = h * 64 + lane;        // output column
  float w[F];
#pragma unroll
  for (int k = 0; k < F; ++k) w[k] = W[(size_t)k * CO + j];
  for (int n = blockIdx.x * NPB + sub; n < N; n += gridDim.x * NPB) {
    const float* ag = agg + (size_t)n * (H * F) + (size_t)h * F;
    float a = 0.f;
#pragma unroll
    for (int k = 0; k < F; ++k) a = fmaf(ag[k], w[k], a);
    if (ELU_ACT) a = (a > 0.f) ? a : expm1f(a);
    out[(size_t)n * CO + j] = a;
  }
}

// ---------------- launch ----------------

extern "C" void kernel_launch(void* const* d_in, const int* in_sizes, int n_in,
                              void* d_out, int out_size, void* d_ws, size_t ws_size,
                              hipStream_t stream) {
  const float* x    = (const float*)d_in[0];
  const int*   ei   = (const int*)d_in[1];
  const float* ea   = (const float*)d_in[2];
  const float* W0   = (const float*)d_in[3];
  const float* We0  = (const float*)d_in[4];
  const float* att0 = (const float*)d_in[5];
  const float* W1   = (const float*)d_in[6];
  const float* We1  = (const float*)d_in[7];
  const float* att1 = (const float*)d_in[8];
  const float* W2   = (const float*)d_in[9];
  const float* We2  = (const float*)d_in[10];
  const float* att2 = (const float*)d_in[11];
  float* out = (float*)d_out;

  const int N = in_sizes[0] / 128;   // 50000
  const int E = in_sizes[2] / 16;    // 800000

  char* p = (char*)d_ws;
  auto alloc = [&](size_t bytes) {
    char* r = p;
    p += (bytes + 255) & ~(size_t)255;
    return r;
  };
  int*   flag = (int*)  alloc(sizeof(int));
  int*   off  = (int*)  alloc((size_t)(N + 1) * sizeof(int));
  int*   cur  = (int*)  alloc((size_t)N * sizeof(int));
  int*   pos  = (int*)  alloc((size_t)E * sizeof(int));
  int*   ssrc = (int*)  alloc((size_t)E * sizeof(int));
  float* waj0 = (float*)alloc(128 * sizeof(float));
  float* wai0 = (float*)alloc(128 * sizeof(float));
  float* waj1 = (float*)alloc(64 * sizeof(float));
  float* wai1 = (float*)alloc(64 * sizeof(float));
  float* waj2 = (float*)alloc(256 * sizeof(float));
  float* wai2 = (float*)alloc(256 * sizeof(float));
  float* ajd  = (float*)alloc((size_t)N * 4 * sizeof(float));
  float* aid  = (float*)alloc((size_t)N * 4 * sizeof(float));
  float* ep0  = (float*)alloc((size_t)E * sizeof(float));
  float* ep1  = (float*)alloc((size_t)E * sizeof(float));
  float* ep2  = (float*)alloc((size_t)E * 4 * sizeof(float));
  float* hbuf = (float*)alloc((size_t)N * 64 * sizeof(float));
  float* agg  = (float*)alloc((size_t)N * 256 * sizeof(float));

  const int eb = (E + THR - 1) / THR;
  const int nb = (N + THR - 1) / THR;
  const int ab = (N + 3) / 4;

  hipMemsetAsync(flag, 0, sizeof(int), stream);
  hipMemsetAsync(cur, 0, (size_t)N * sizeof(int), stream);

  k_detect<<<16, THR, 0, stream>>>(ei, flag);
  k_count<<<eb, THR, 0, stream>>>(ei, flag, cur, E);
  k_scan<<<1, 1024, 0, stream>>>(cur, off, N);
  k_scatter<<<eb, THR, 0, stream>>>(ei, flag, cur, pos, ssrc, E);

  k_fold_att<<<1, 128, 0, stream>>>(W0, att0, waj0, wai0, 128, 1);
  k_fold_att<<<1, 64, 0, stream>>>(W1, att1, waj1, wai1, 64, 1);
  k_fold_att<<<1, 256, 0, stream>>>(W2, att2, waj2, wai2, 64, 4);
  k_ep<<<eb, THR, 0, stream>>>(ea, We0, We1, We2, att0, att1, att2, pos,
                               ep0, ep1, ep2, E);

  // layer 0: Cin=128, H=1
  k_node_dots<128, 1><<<nb, THR, 0, stream>>>(x, waj0, wai0, ajd, aid, N);
  k_attn_agg<128, 1><<<ab, THR, 0, stream>>>(off, ssrc, x, ajd, aid, ep0, agg, N);
  k_post_reg<128, 1, true><<<1024, THR, 0, stream>>>(agg, W0, hbuf, N);

  // layer 1: Cin=64, H=1
  k_node_dots<64, 1><<<nb, THR, 0, stream>>>(hbuf, waj1, wai1, ajd, aid, N);
  k_attn_agg<64, 1><<<ab, THR, 0, stream>>>(off, ssrc, hbuf, ajd, aid, ep1, agg, N);
  k_post_reg<64, 1, true><<<1024, THR, 0, stream>>>(agg, W1, hbuf, N);

  // layer 2: Cin=64, H=4 (all heads in one wave)
  k_node_dots<64, 4><<<nb, THR, 0, stream>>>(hbuf, waj2, wai2, ajd, aid, N);
  k_attn_agg<64, 4><<<ab, THR, 0, stream>>>(off, ssrc, hbuf, ajd, aid, ep2, agg, N);
  k_post_reg<64, 4, false><<<1024, THR, 0, stream>>>(agg, W2, out, N);
}

// Round 9
// 728.738 us; speedup vs baseline: 1.1665x; 1.0636x over previous
//
#include <hip/hip_runtime.h>
#include <math.h>

#define THR 256

typedef __attribute__((ext_vector_type(8))) short bf16x8;
typedef __attribute__((ext_vector_type(4))) float f32x4;

// ---------------- CSR build ----------------

// Detect whether edge_index buffer is int64 (high words all zero) or int32.
__global__ void k_detect(const int* __restrict__ w, int* __restrict__ flag) {
  int i = blockIdx.x * blockDim.x + threadIdx.x;
  if (i < 4096) {
    if (w[2 * i + 1] != 0) atomicOr(flag, 1);
  }
}

__device__ __forceinline__ int load_idx(const int* __restrict__ w, int pos, int is32) {
  return is32 ? w[pos] : w[2 * pos];
}

__global__ void k_count(const int* __restrict__ ei, const int* __restrict__ flag,
                        int* __restrict__ cnt, int E) {
  int e = blockIdx.x * blockDim.x + threadIdx.x;
  if (e < E) {
    int is32 = *flag;
    int d = load_idx(ei, E + e, is32);
    atomicAdd(&cnt[d], 1);
  }
}

__global__ __launch_bounds__(1024) void k_scan(int* __restrict__ cnt_cur, int* __restrict__ off, int n) {
  __shared__ int part[1024];
  int tid = threadIdx.x;
  int chunk = (n + 1023) / 1024;
  int s0 = tid * chunk;
  int s1 = min(s0 + chunk, n);
  int s = 0;
  for (int i = s0; i < s1; ++i) s += cnt_cur[i];
  part[tid] = s;
  __syncthreads();
  for (int d = 1; d < 1024; d <<= 1) {
    int v = (tid >= d) ? part[tid - d] : 0;
    __syncthreads();
    part[tid] += v;
    __syncthreads();
  }
  int excl = (tid == 0) ? 0 : part[tid - 1];
  for (int i = s0; i < s1; ++i) {
    int c = cnt_cur[i];
    off[i] = excl;
    cnt_cur[i] = excl;   // cursor copy for scatter
    excl += c;
  }
  if (tid == 1023) off[n] = part[1023];
}

__global__ void k_scatter(const int* __restrict__ ei, const int* __restrict__ flag,
                          int* __restrict__ cur, int* __restrict__ pos,
                          int* __restrict__ ssrc, int E) {
  int e = blockIdx.x * blockDim.x + threadIdx.x;
  if (e < E) {
    int is32 = *flag;
    int d = load_idx(ei, E + e, is32);
    int s = load_idx(ei, e, is32);
    int p = atomicAdd(&cur[d], 1);
    pos[e] = p;
    ssrc[p] = s;
  }
}

// ---------------- weight prep ----------------

__global__ void k_fold_att(const float* __restrict__ W, const float* __restrict__ att,
                           float* __restrict__ waj, float* __restrict__ wai,
                           int Cin, int H) {
  int i = blockIdx.x * blockDim.x + threadIdx.x;
  if (i >= Cin * H) return;
  int k = i / H, h = i % H;
  float sj = 0.f, si = 0.f;
  for (int d = 0; d < 64; ++d) {
    float w = W[k * (H * 64) + h * 64 + d];
    sj = fmaf(w, att[h * 192 + d], sj);
    si = fmaf(w, att[h * 192 + 64 + d], si);
  }
  waj[k * H + h] = sj;
  wai[k * H + h] = si;
}

template <int CIN, int H>
__global__ void k_node_dots(const float* __restrict__ xin, const float* __restrict__ waj,
                            const float* __restrict__ wai, float* __restrict__ ajd,
                            float* __restrict__ aid, int N) {
  int n = blockIdx.x * blockDim.x + threadIdx.x;
  if (n >= N) return;
  float sj[H], si[H];
#pragma unroll
  for (int h = 0; h < H; ++h) { sj[h] = 0.f; si[h] = 0.f; }
  const float* xr = xin + (size_t)n * CIN;
#pragma unroll 4
  for (int k = 0; k < CIN; ++k) {
    float xv = xr[k];
#pragma unroll
    for (int h = 0; h < H; ++h) {
      sj[h] = fmaf(xv, waj[k * H + h], sj[h]);
      si[h] = fmaf(xv, wai[k * H + h], si[h]);
    }
  }
#pragma unroll
  for (int h = 0; h < H; ++h) {
    ajd[(size_t)n * H + h] = sj[h];
    aid[(size_t)n * H + h] = si[h];
  }
}

// ---------------- MFMA-based edge scalar ep ----------------

__device__ __forceinline__ unsigned short bf16_rne(float x) {
  unsigned int u = __float_as_uint(x);
  return (unsigned short)((u + 0x7FFFu + ((u >> 16) & 1u)) >> 16);
}

// Build B fragments for the 16x16x32 bf16 MFMA.
// Concat weight matrix We_cat: 16 x 384 (cols 0-63 We0, 64-127 We1, 128-383 We2).
// Split f32 = hi + lo (bf16 each). K=32 arrangement: k<16 -> pairs with Ahi,
// k>=16 -> pairs with Alo.  B1 = [Bhi;Bhi], B2 = [Blo;0].
// Fragment layout: lane l holds col = T*16 + (l&15), k = (l>>4)*8 + j, j=0..7.
// avec[384]: the a_p coefficient for each concat column.
__global__ void k_prep_b(const float* __restrict__ We0, const float* __restrict__ We1,
                         const float* __restrict__ We2,
                         const float* __restrict__ att0, const float* __restrict__ att1,
                         const float* __restrict__ att2,
                         bf16x8* __restrict__ B1, bf16x8* __restrict__ B2,
                         float* __restrict__ avec) {
  int i = blockIdx.x * blockDim.x + threadIdx.x;
  if (i < 24 * 64) {
    int T = i >> 6, l = i & 63;
    int col = T * 16 + (l & 15);
    int grp = l >> 4;
    bf16x8 b1, b2;
#pragma unroll
    for (int j = 0; j < 8; ++j) {
      int kk = grp * 8 + j;     // 0..31
      int ks = kk & 15;         // source k (both halves use same Bhi)
      float w;
      if (col < 64)        w = We0[ks * 64 + col];
      else if (col < 128)  w = We1[ks * 64 + (col - 64)];
      else                 w = We2[ks * 256 + (col - 128)];
      unsigned short hi = bf16_rne(w);
      float hif = __uint_as_float((unsigned int)hi << 16);
      unsigned short lo = bf16_rne(w - hif);
      b1[j] = (short)hi;
      b2[j] = (kk < 16) ? (short)lo : (short)0;
    }
    B1[i] = b1;
    B2[i] = b2;
  } else if (i < 24 * 64 + 384) {
    int col = i - 24 * 64;
    float a;
    if (col < 64)        a = att0[128 + col];
    else if (col < 128)  a = att1[128 + (col - 64)];
    else {
      int c = col - 128;
      a = att2[(c >> 6) * 192 + 128 + (c & 63)];
    }
    avec[col] = a;
  }
}

// One wave = 64 edges (4 A-fragments of 16 rows).  24 col-tiles over the 384
// concatenated outputs; 2 chained MFMAs per (frag, tile) give bf16x3 precision
// (AhiBhi + AloBhi + AhiBlo).  Epilogue: relu * a, accumulate per segment of 4
// tiles (=64 d), reduce across the 16 col-lanes, scatter to CSR position.
__global__ __launch_bounds__(256) void k_ep_mfma(
    const float* __restrict__ ea, const bf16x8* __restrict__ B1,
    const bf16x8* __restrict__ B2, const float* __restrict__ avec,
    const int* __restrict__ pos, float* __restrict__ ep0,
    float* __restrict__ ep1, float* __restrict__ ep2, int E) {
  const int lane = threadIdx.x & 63;
  const int wv = threadIdx.x >> 6;
  const long e0 = ((long)blockIdx.x * 4 + wv) * 64;
  const int grp = lane >> 4;        // 0..3
  const int row = lane & 15;        // A: M-row within fragment
  const int kc = (grp & 1) * 8;     // which 8 source-k's this lane group loads
  const bool lo_grp = grp >= 2;     // groups 2,3 carry the lo halves (k 16..31)

  // ---- A fragments ----
  bf16x8 A[4];
#pragma unroll
  for (int f = 0; f < 4; ++f) {
    long e = e0 + f * 16 + row;
    if (e >= E) e = E - 1;          // clamp; stores guarded later
    const float* ar = ea + e * 16 + kc;
    float4 u0 = *reinterpret_cast<const float4*>(ar);
    float4 u1 = *reinterpret_cast<const float4*>(ar + 4);
    float v0 = u0.x, v1 = u0.y, v2 = u0.z, v3 = u0.w;
    float v4 = u1.x, v5 = u1.y, v6 = u1.z, v7 = u1.w;
    bf16x8 a;
#define CVT(J, V)                                                        \
    {                                                                    \
      unsigned short hi = bf16_rne(V);                                   \
      float hif = __uint_as_float((unsigned int)hi << 16);               \
      unsigned short lo = bf16_rne((V) - hif);                           \
      a[J] = (short)(lo_grp ? lo : hi);                                  \
    }
    CVT(0, v0) CVT(1, v1) CVT(2, v2) CVT(3, v3)
    CVT(4, v4) CVT(5, v5) CVT(6, v6) CVT(7, v7)
#undef CVT
    A[f] = a;
  }

  // ---- 6 segments × 4 tiles ----
#pragma unroll
  for (int seg = 0; seg < 6; ++seg) {
    float sp[4][4];
#pragma unroll
    for (int f = 0; f < 4; ++f)
#pragma unroll
      for (int r = 0; r < 4; ++r) sp[f][r] = 0.f;

#pragma unroll
    for (int tt = 0; tt < 4; ++tt) {
      const int T = seg * 4 + tt;
      bf16x8 b1 = B1[T * 64 + lane];
      bf16x8 b2 = B2[T * 64 + lane];
      float aval = avec[T * 16 + row];
#pragma unroll
      for (int f = 0; f < 4; ++f) {
        f32x4 acc = {0.f, 0.f, 0.f, 0.f};
        acc = __builtin_amdgcn_mfma_f32_16x16x32_bf16(A[f], b1, acc, 0, 0, 0);
        acc = __builtin_amdgcn_mfma_f32_16x16x32_bf16(A[f], b2, acc, 0, 0, 0);
#pragma unroll
        for (int r = 0; r < 4; ++r)
          sp[f][r] = fmaf(fmaxf(acc[r], 0.f), aval, sp[f][r]);
      }
    }

    // reduce over the 16 col-lanes within each group
#pragma unroll
    for (int o = 1; o < 16; o <<= 1)
#pragma unroll
      for (int f = 0; f < 4; ++f)
#pragma unroll
        for (int r = 0; r < 4; ++r)
          sp[f][r] += __shfl_xor(sp[f][r], o, 64);

    if (row == 0) {
      // lane grp*16 holds D-rows grp*4+r of each fragment
#pragma unroll
      for (int f = 0; f < 4; ++f)
#pragma unroll
        for (int r = 0; r < 4; ++r) {
          long e = e0 + f * 16 + grp * 4 + r;
          if (e < E) {
            int p = pos[e];
            if (seg == 0)      ep0[p] = sp[f][r];
            else if (seg == 1) ep1[p] = sp[f][r];
            else               ep2[(size_t)p * 4 + (seg - 2)] = sp[f][r];
          }
        }
    }
  }
}

// ---------------- fused attention softmax + aggregate ----------------

template <int H>
__device__ __forceinline__ void loadH(const float* __restrict__ p, float* v) {
  if constexpr (H == 4) {
    float4 t = *reinterpret_cast<const float4*>(p);
    v[0] = t.x; v[1] = t.y; v[2] = t.z; v[3] = t.w;
  } else {
    v[0] = *p;
  }
}

// one wave per node, all H heads together.
// agg[n, h*F + f] = sum_e alpha_{e,h} * hin[src_e, f]
template <int F, int H>
__global__ __launch_bounds__(256) void k_attn_agg(
    const int* __restrict__ off, const int* __restrict__ ssrc,
    const float* __restrict__ hin, const float* __restrict__ ajd,
    const float* __restrict__ aid, const float* __restrict__ ep,
    float* __restrict__ outbuf, int N) {
  constexpr int FPL = F / 64;
  __shared__ float ls_alpha[4][64 * H];
  __shared__ int ls_src[4][64];
  const int wave = threadIdx.x >> 6, lane = threadIdx.x & 63;
  float* const la = ls_alpha[wave];
  int* const lsrc = ls_src[wave];

  for (int n = blockIdx.x * 4 + wave; n < N; n += gridDim.x * 4) {
    const int o0 = off[n];
    const int deg = off[n + 1] - o0;
    float aidn[H];
    loadH<H>(aid + (size_t)n * H, aidn);

    // ---- pass 1: online softmax stats (lane-parallel over edges) ----
    float m[H], s[H];
#pragma unroll
    for (int h = 0; h < H; ++h) { m[h] = -1e30f; s[h] = 0.f; }
    for (int i = lane; i < deg; i += 64) {
      int sr = ssrc[o0 + i];
      float aj[H], pv[H];
      loadH<H>(ajd + (size_t)sr * H, aj);
      loadH<H>(ep + (size_t)(o0 + i) * H, pv);
#pragma unroll
      for (int h = 0; h < H; ++h) {
        float sc = aj[h] + aidn[h] + pv[h];
        sc = sc > 0.f ? sc : 0.2f * sc;
        float mn = fmaxf(m[h], sc);
        s[h] = s[h] * __expf(m[h] - mn) + __expf(sc - mn);
        m[h] = mn;
      }
    }
#pragma unroll
    for (int o = 32; o > 0; o >>= 1) {
#pragma unroll
      for (int h = 0; h < H; ++h) {
        float m2 = __shfl_xor(m[h], o, 64);
        float s2 = __shfl_xor(s[h], o, 64);
        float mn = fmaxf(m[h], m2);
        s[h] = s[h] * __expf(m[h] - mn) + s2 * __expf(m2 - mn);
        m[h] = mn;
      }
    }
    float inv[H];
#pragma unroll
    for (int h = 0; h < H; ++h) inv[h] = 1.f / (s[h] + 1e-16f);

    // ---- pass 2: chunked alpha -> LDS, then 4-way unrolled gather+FMA ----
    float acc[H][FPL];
#pragma unroll
    for (int h = 0; h < H; ++h)
#pragma unroll
      for (int c = 0; c < FPL; ++c) acc[h][c] = 0.f;

    for (int base = 0; base < deg; base += 64) {
      const int cnt = min(64, deg - base);
      if (lane < cnt) {
        int i = base + lane;
        int sr = ssrc[o0 + i];
        lsrc[lane] = sr;
        float aj[H], pv[H];
        loadH<H>(ajd + (size_t)sr * H, aj);
        loadH<H>(ep + (size_t)(o0 + i) * H, pv);
#pragma unroll
        for (int h = 0; h < H; ++h) {
          float sc = aj[h] + aidn[h] + pv[h];
          sc = sc > 0.f ? sc : 0.2f * sc;
          la[lane * H + h] = __expf(sc - m[h]) * inv[h];
        }
      }
      asm volatile("s_waitcnt lgkmcnt(0)" ::: "memory");

      int j = 0;
      for (; j + 4 <= cnt; j += 4) {
        int srj[4];
        float av[4][H];
#pragma unroll
        for (int u = 0; u < 4; ++u) {
          srj[u] = lsrc[j + u];
          loadH<H>(la + (j + u) * H, av[u]);
        }
        float v[4][FPL];
#pragma unroll
        for (int u = 0; u < 4; ++u) {
          const float* hr = hin + (size_t)srj[u] * F + lane;
#pragma unroll
          for (int c = 0; c < FPL; ++c) v[u][c] = hr[c * 64];
        }
#pragma unroll
        for (int u = 0; u < 4; ++u)
#pragma unroll
          for (int h = 0; h < H; ++h)
#pragma unroll
            for (int c = 0; c < FPL; ++c)
              acc[h][c] = fmaf(av[u][h], v[u][c], acc[h][c]);
      }
      for (; j < cnt; ++j) {
        int sr = lsrc[j];
        float av[H];
        loadH<H>(la + j * H, av);
        const float* hr = hin + (size_t)sr * F + lane;
#pragma unroll
        for (int h = 0; h < H; ++h)
#pragma unroll
          for (int c = 0; c < FPL; ++c)
            acc[h][c] = fmaf(av[h], hr[c * 64], acc[h][c]);
      }
    }

    float* ob = outbuf + (size_t)n * (H * F);
#pragma unroll
    for (int h = 0; h < H; ++h)
#pragma unroll
      for (int c = 0; c < FPL; ++c) ob[h * F + c * 64 + lane] = acc[h][c];
  }
}

// ---------------- post GEMM: out[n, h*64+j] = agg[n,h,:] @ W[:, h*64+j] (+ELU) ----------------
// Weights live in per-thread registers (thread owns output column j).
// Activations ag[n,h,:] are wave-uniform -> scalar loads; no LDS traffic.

template <int F, int H, bool ELU_ACT>
__global__ __launch_bounds__(256) void k_post_reg(const float* __restrict__ agg,
                                                  const float* __restrict__ W,
                                                  float* __restrict__ out, int N) {
  constexpr int CO = H * 64;
  constexpr int NPB = 256 / CO;       // nodes per block-iteration
  const int tid = threadIdx.x;
  const int wave = tid >> 6;
  const int lane = tid & 63;
  const int sub = wave / H;           // node sub-index within block
  const int h = wave % H;
  const int j = h * 64 + lane;        // output column
  float w[F];
#pragma unroll
  for (int k = 0; k < F; ++k) w[k] = W[(size_t)k * CO + j];
  for (int n = blockIdx.x * NPB + sub; n < N; n += gridDim.x * NPB) {
    const float* ag = agg + (size_t)n * (H * F) + (size_t)h * F;
    float a = 0.f;
#pragma unroll
    for (int k = 0; k < F; ++k) a = fmaf(ag[k], w[k], a);
    if (ELU_ACT) a = (a > 0.f) ? a : expm1f(a);
    out[(size_t)n * CO + j] = a;
  }
}

// ---------------- launch ----------------

extern "C" void kernel_launch(void* const* d_in, const int* in_sizes, int n_in,
                              void* d_out, int out_size, void* d_ws, size_t ws_size,
                              hipStream_t stream) {
  const float* x    = (const float*)d_in[0];
  const int*   ei   = (const int*)d_in[1];
  const float* ea   = (const float*)d_in[2];
  const float* W0   = (const float*)d_in[3];
  const float* We0  = (const float*)d_in[4];
  const float* att0 = (const float*)d_in[5];
  const float* W1   = (const float*)d_in[6];
  const float* We1  = (const float*)d_in[7];
  const float* att1 = (const float*)d_in[8];
  const float* W2   = (const float*)d_in[9];
  const float* We2  = (const float*)d_in[10];
  const float* att2 = (const float*)d_in[11];
  float* out = (float*)d_out;

  const int N = in_sizes[0] / 128;   // 50000
  const int E = in_sizes[2] / 16;    // 800000

  char* p = (char*)d_ws;
  auto alloc = [&](size_t bytes) {
    char* r = p;
    p += (bytes + 255) & ~(size_t)255;
    return r;
  };
  int*   flag = (int*)  alloc(sizeof(int));
  int*   off  = (int*)  alloc((size_t)(N + 1) * sizeof(int));
  int*   cur  = (int*)  alloc((size_t)N * sizeof(int));
  int*   pos  = (int*)  alloc((size_t)E * sizeof(int));
  int*   ssrc = (int*)  alloc((size_t)E * sizeof(int));
  bf16x8* B1  = (bf16x8*)alloc(24 * 64 * sizeof(bf16x8));
  bf16x8* B2  = (bf16x8*)alloc(24 * 64 * sizeof(bf16x8));
  float* avec = (float*)alloc(384 * sizeof(float));
  float* waj0 = (float*)alloc(128 * sizeof(float));
  float* wai0 = (float*)alloc(128 * sizeof(float));
  float* waj1 = (float*)alloc(64 * sizeof(float));
  float* wai1 = (float*)alloc(64 * sizeof(float));
  float* waj2 = (float*)alloc(256 * sizeof(float));
  float* wai2 = (float*)alloc(256 * sizeof(float));
  float* ajd  = (float*)alloc((size_t)N * 4 * sizeof(float));
  float* aid  = (float*)alloc((size_t)N * 4 * sizeof(float));
  float* ep0  = (float*)alloc((size_t)E * sizeof(float));
  float* ep1  = (float*)alloc((size_t)E * sizeof(float));
  float* ep2  = (float*)alloc((size_t)E * 4 * sizeof(float));
  float* hbuf = (float*)alloc((size_t)N * 64 * sizeof(float));
  float* agg  = (float*)alloc((size_t)N * 256 * sizeof(float));

  const int eb = (E + THR - 1) / THR;
  const int nb = (N + THR - 1) / THR;
  const int ab = (N + 3) / 4;

  hipMemsetAsync(flag, 0, sizeof(int), stream);
  hipMemsetAsync(cur, 0, (size_t)N * sizeof(int), stream);

  k_detect<<<16, THR, 0, stream>>>(ei, flag);
  k_count<<<eb, THR, 0, stream>>>(ei, flag, cur, E);
  k_scan<<<1, 1024, 0, stream>>>(cur, off, N);
  k_scatter<<<eb, THR, 0, stream>>>(ei, flag, cur, pos, ssrc, E);

  k_fold_att<<<1, 128, 0, stream>>>(W0, att0, waj0, wai0, 128, 1);
  k_fold_att<<<1, 64, 0, stream>>>(W1, att1, waj1, wai1, 64, 1);
  k_fold_att<<<1, 256, 0, stream>>>(W2, att2, waj2, wai2, 64, 4);

  k_prep_b<<<8, THR, 0, stream>>>(We0, We1, We2, att0, att1, att2, B1, B2, avec);
  // 256 edges per block (4 waves x 64 edges)
  k_ep_mfma<<<(E + 255) / 256, THR, 0, stream>>>(ea, B1, B2, avec, pos,
                                                 ep0, ep1, ep2, E);

  // layer 0: Cin=128, H=1
  k_node_dots<128, 1><<<nb, THR, 0, stream>>>(x, waj0, wai0, ajd, aid, N);
  k_attn_agg<128, 1><<<ab, THR, 0, stream>>>(off, ssrc, x, ajd, aid, ep0, agg, N);
  k_post_reg<128, 1, true><<<1024, THR, 0, stream>>>(agg, W0, hbuf, N);

  // layer 1: Cin=64, H=1
  k_node_dots<64, 1><<<nb, THR, 0, stream>>>(hbuf, waj1, wai1, ajd, aid, N);
  k_attn_agg<64, 1><<<ab, THR, 0, stream>>>(off, ssrc, hbuf, ajd, aid, ep1, agg, N);
  k_post_reg<64, 1, true><<<1024, THR, 0, stream>>>(agg, W1, hbuf, N);

  // layer 2: Cin=64, H=4 (all heads in one wave)
  k_node_dots<64, 4><<<nb, THR, 0, stream>>>(hbuf, waj2, wai2, ajd, aid, N);
  k_attn_agg<64, 4><<<ab, THR, 0, stream>>>(off, ssrc, hbuf, ajd, aid, ep2, agg, N);
  k_post_reg<64, 4, false><<<1024, THR, 0, stream>>>(agg, W2, out, N);
}

// Round 10
// 695.331 us; speedup vs baseline: 1.2226x; 1.0480x over previous
//
#include <hip/hip_runtime.h>
#include <math.h>

#define THR 256

typedef __attribute__((ext_vector_type(8))) short bf16x8;
typedef __attribute__((ext_vector_type(4))) float f32x4;

// ---------------- CSR build ----------------

// Detect whether edge_index buffer is int64 (high words all zero) or int32.
__global__ void k_detect(const int* __restrict__ w, int* __restrict__ flag) {
  int i = blockIdx.x * blockDim.x + threadIdx.x;
  if (i < 4096) {
    if (w[2 * i + 1] != 0) atomicOr(flag, 1);
  }
}

__device__ __forceinline__ int load_idx(const int* __restrict__ w, int pos, int is32) {
  return is32 ? w[pos] : w[2 * pos];
}

__global__ void k_count(const int* __restrict__ ei, const int* __restrict__ flag,
                        int* __restrict__ cnt, int E) {
  int e = blockIdx.x * blockDim.x + threadIdx.x;
  if (e < E) {
    int is32 = *flag;
    int d = load_idx(ei, E + e, is32);
    atomicAdd(&cnt[d], 1);
  }
}

__global__ __launch_bounds__(1024) void k_scan(int* __restrict__ cnt_cur, int* __restrict__ off, int n) {
  __shared__ int part[1024];
  int tid = threadIdx.x;
  int chunk = (n + 1023) / 1024;
  int s0 = tid * chunk;
  int s1 = min(s0 + chunk, n);
  int s = 0;
  for (int i = s0; i < s1; ++i) s += cnt_cur[i];
  part[tid] = s;
  __syncthreads();
  for (int d = 1; d < 1024; d <<= 1) {
    int v = (tid >= d) ? part[tid - d] : 0;
    __syncthreads();
    part[tid] += v;
    __syncthreads();
  }
  int excl = (tid == 0) ? 0 : part[tid - 1];
  for (int i = s0; i < s1; ++i) {
    int c = cnt_cur[i];
    off[i] = excl;
    cnt_cur[i] = excl;   // cursor copy for scatter
    excl += c;
  }
  if (tid == 1023) off[n] = part[1023];
}

__global__ void k_scatter(const int* __restrict__ ei, const int* __restrict__ flag,
                          int* __restrict__ cur, int* __restrict__ pos,
                          int* __restrict__ ssrc, int E) {
  int e = blockIdx.x * blockDim.x + threadIdx.x;
  if (e < E) {
    int is32 = *flag;
    int d = load_idx(ei, E + e, is32);
    int s = load_idx(ei, e, is32);
    int p = atomicAdd(&cur[d], 1);
    pos[e] = p;
    ssrc[p] = s;
  }
}

// ---------------- weight prep (layer 2 only) ----------------

__global__ void k_fold_att(const float* __restrict__ W, const float* __restrict__ att,
                           float* __restrict__ waj, float* __restrict__ wai,
                           int Cin, int H) {
  int i = blockIdx.x * blockDim.x + threadIdx.x;
  if (i >= Cin * H) return;
  int k = i / H, h = i % H;
  float sj = 0.f, si = 0.f;
  for (int d = 0; d < 64; ++d) {
    float w = W[k * (H * 64) + h * 64 + d];
    sj = fmaf(w, att[h * 192 + d], sj);
    si = fmaf(w, att[h * 192 + 64 + d], si);
  }
  waj[k * H + h] = sj;
  wai[k * H + h] = si;
}

template <int CIN, int H>
__global__ void k_node_dots(const float* __restrict__ xin, const float* __restrict__ waj,
                            const float* __restrict__ wai, float* __restrict__ ajd,
                            float* __restrict__ aid, int N) {
  int n = blockIdx.x * blockDim.x + threadIdx.x;
  if (n >= N) return;
  float sj[H], si[H];
#pragma unroll
  for (int h = 0; h < H; ++h) { sj[h] = 0.f; si[h] = 0.f; }
  const float* xr = xin + (size_t)n * CIN;
#pragma unroll 4
  for (int k = 0; k < CIN; ++k) {
    float xv = xr[k];
#pragma unroll
    for (int h = 0; h < H; ++h) {
      sj[h] = fmaf(xv, waj[k * H + h], sj[h]);
      si[h] = fmaf(xv, wai[k * H + h], si[h]);
    }
  }
#pragma unroll
  for (int h = 0; h < H; ++h) {
    ajd[(size_t)n * H + h] = sj[h];
    aid[(size_t)n * H + h] = si[h];
  }
}

// ---------------- per-node projection GEMM with fused att-dots (layers 0,1) ----------------
// xh[n,j] = sum_k xin[n,k] * W[k,j]   (64 output cols, lane j owns col j)
// ajd[n]  = sum_j xh[n,j] * att[j] ;  aid[n] = sum_j xh[n,j] * att[64+j]
template <int F>
__global__ __launch_bounds__(256) void k_gemm_nh(
    const float* __restrict__ xin, const float* __restrict__ W,
    const float* __restrict__ att, float* __restrict__ xh,
    float* __restrict__ ajd, float* __restrict__ aid, int N) {
  const int wave = threadIdx.x >> 6, lane = threadIdx.x & 63;
  float w[F];
#pragma unroll
  for (int k = 0; k < F; ++k) w[k] = W[k * 64 + lane];
  const float aj = att[lane], ai = att[64 + lane];
  for (int n = blockIdx.x * 4 + wave; n < N; n += gridDim.x * 4) {
    const float* xr = xin + (size_t)n * F;
    float a = 0.f;
#pragma unroll
    for (int k = 0; k < F; ++k) a = fmaf(xr[k], w[k], a);
    xh[(size_t)n * 64 + lane] = a;
    float sj = a * aj, si = a * ai;
#pragma unroll
    for (int o = 32; o > 0; o >>= 1) {
      sj += __shfl_xor(sj, o, 64);
      si += __shfl_xor(si, o, 64);
    }
    if (lane == 0) { ajd[n] = sj; aid[n] = si; }
  }
}

// ---------------- MFMA-based edge scalar ep ----------------

__device__ __forceinline__ unsigned short bf16_rne(float x) {
  unsigned int u = __float_as_uint(x);
  return (unsigned short)((u + 0x7FFFu + ((u >> 16) & 1u)) >> 16);
}

// Build B fragments for the 16x16x32 bf16 MFMA.
// Concat weight matrix We_cat: 16 x 384 (cols 0-63 We0, 64-127 We1, 128-383 We2).
// Split f32 = hi + lo (bf16 each). K=32 arrangement: k<16 -> pairs with Ahi,
// k>=16 -> pairs with Alo.  B1 = [Bhi;Bhi], B2 = [Blo;0].
// Fragment layout: lane l holds col = T*16 + (l&15), k = (l>>4)*8 + j, j=0..7.
// avec[384]: the a_p coefficient for each concat column.
__global__ void k_prep_b(const float* __restrict__ We0, const float* __restrict__ We1,
                         const float* __restrict__ We2,
                         const float* __restrict__ att0, const float* __restrict__ att1,
                         const float* __restrict__ att2,
                         bf16x8* __restrict__ B1, bf16x8* __restrict__ B2,
                         float* __restrict__ avec) {
  int i = blockIdx.x * blockDim.x + threadIdx.x;
  if (i < 24 * 64) {
    int T = i >> 6, l = i & 63;
    int col = T * 16 + (l & 15);
    int grp = l >> 4;
    bf16x8 b1, b2;
#pragma unroll
    for (int j = 0; j < 8; ++j) {
      int kk = grp * 8 + j;     // 0..31
      int ks = kk & 15;         // source k (both halves use same Bhi)
      float w;
      if (col < 64)        w = We0[ks * 64 + col];
      else if (col < 128)  w = We1[ks * 64 + (col - 64)];
      else                 w = We2[ks * 256 + (col - 128)];
      unsigned short hi = bf16_rne(w);
      float hif = __uint_as_float((unsigned int)hi << 16);
      unsigned short lo = bf16_rne(w - hif);
      b1[j] = (short)hi;
      b2[j] = (kk < 16) ? (short)lo : (short)0;
    }
    B1[i] = b1;
    B2[i] = b2;
  } else if (i < 24 * 64 + 384) {
    int col = i - 24 * 64;
    float a;
    if (col < 64)        a = att0[128 + col];
    else if (col < 128)  a = att1[128 + (col - 64)];
    else {
      int c = col - 128;
      a = att2[(c >> 6) * 192 + 128 + (c & 63)];
    }
    avec[col] = a;
  }
}

// One wave = 64 edges (4 A-fragments of 16 rows).  24 col-tiles over the 384
// concatenated outputs; 2 chained MFMAs per (frag, tile) give bf16x3 precision
// (AhiBhi + AloBhi + AhiBlo).  Epilogue: relu * a, accumulate per segment of 4
// tiles (=64 d), reduce across the 16 col-lanes, scatter to CSR position.
__global__ __launch_bounds__(256) void k_ep_mfma(
    const float* __restrict__ ea, const bf16x8* __restrict__ B1,
    const bf16x8* __restrict__ B2, const float* __restrict__ avec,
    const int* __restrict__ pos, float* __restrict__ ep0,
    float* __restrict__ ep1, float* __restrict__ ep2, int E) {
  const int lane = threadIdx.x & 63;
  const int wv = threadIdx.x >> 6;
  const long e0 = ((long)blockIdx.x * 4 + wv) * 64;
  const int grp = lane >> 4;        // 0..3
  const int row = lane & 15;        // A: M-row within fragment
  const int kc = (grp & 1) * 8;     // which 8 source-k's this lane group loads
  const bool lo_grp = grp >= 2;     // groups 2,3 carry the lo halves (k 16..31)

  // ---- A fragments ----
  bf16x8 A[4];
#pragma unroll
  for (int f = 0; f < 4; ++f) {
    long e = e0 + f * 16 + row;
    if (e >= E) e = E - 1;          // clamp; stores guarded later
    const float* ar = ea + e * 16 + kc;
    float4 u0 = *reinterpret_cast<const float4*>(ar);
    float4 u1 = *reinterpret_cast<const float4*>(ar + 4);
    float v0 = u0.x, v1 = u0.y, v2 = u0.z, v3 = u0.w;
    float v4 = u1.x, v5 = u1.y, v6 = u1.z, v7 = u1.w;
    bf16x8 a;
#define CVT(J, V)                                                        \
    {                                                                    \
      unsigned short hi = bf16_rne(V);                                   \
      float hif = __uint_as_float((unsigned int)hi << 16);               \
      unsigned short lo = bf16_rne((V) - hif);                           \
      a[J] = (short)(lo_grp ? lo : hi);                                  \
    }
    CVT(0, v0) CVT(1, v1) CVT(2, v2) CVT(3, v3)
    CVT(4, v4) CVT(5, v5) CVT(6, v6) CVT(7, v7)
#undef CVT
    A[f] = a;
  }

  // ---- 6 segments × 4 tiles ----
#pragma unroll
  for (int seg = 0; seg < 6; ++seg) {
    float sp[4][4];
#pragma unroll
    for (int f = 0; f < 4; ++f)
#pragma unroll
      for (int r = 0; r < 4; ++r) sp[f][r] = 0.f;

#pragma unroll
    for (int tt = 0; tt < 4; ++tt) {
      const int T = seg * 4 + tt;
      bf16x8 b1 = B1[T * 64 + lane];
      bf16x8 b2 = B2[T * 64 + lane];
      float aval = avec[T * 16 + row];
#pragma unroll
      for (int f = 0; f < 4; ++f) {
        f32x4 acc = {0.f, 0.f, 0.f, 0.f};
        acc = __builtin_amdgcn_mfma_f32_16x16x32_bf16(A[f], b1, acc, 0, 0, 0);
        acc = __builtin_amdgcn_mfma_f32_16x16x32_bf16(A[f], b2, acc, 0, 0, 0);
#pragma unroll
        for (int r = 0; r < 4; ++r)
          sp[f][r] = fmaf(fmaxf(acc[r], 0.f), aval, sp[f][r]);
      }
    }

    // reduce over the 16 col-lanes within each group
#pragma unroll
    for (int o = 1; o < 16; o <<= 1)
#pragma unroll
      for (int f = 0; f < 4; ++f)
#pragma unroll
        for (int r = 0; r < 4; ++r)
          sp[f][r] += __shfl_xor(sp[f][r], o, 64);

    if (row == 0) {
      // lane grp*16 holds D-rows grp*4+r of each fragment
#pragma unroll
      for (int f = 0; f < 4; ++f)
#pragma unroll
        for (int r = 0; r < 4; ++r) {
          long e = e0 + f * 16 + grp * 4 + r;
          if (e < E) {
            int p = pos[e];
            if (seg == 0)      ep0[p] = sp[f][r];
            else if (seg == 1) ep1[p] = sp[f][r];
            else               ep2[(size_t)p * 4 + (seg - 2)] = sp[f][r];
          }
        }
    }
  }
}

// ---------------- fused attention softmax + aggregate ----------------

template <int H>
__device__ __forceinline__ void loadH(const float* __restrict__ p, float* v) {
  if constexpr (H == 4) {
    float4 t = *reinterpret_cast<const float4*>(p);
    v[0] = t.x; v[1] = t.y; v[2] = t.z; v[3] = t.w;
  } else {
    v[0] = *p;
  }
}

// one wave per node, all H heads together.
// agg[n, h*F + f] = sum_e alpha_{e,h} * hin[src_e, f]   (+ optional ELU)
template <int F, int H, bool ELU_OUT>
__global__ __launch_bounds__(256) void k_attn_agg(
    const int* __restrict__ off, const int* __restrict__ ssrc,
    const float* __restrict__ hin, const float* __restrict__ ajd,
    const float* __restrict__ aid, const float* __restrict__ ep,
    float* __restrict__ outbuf, int N) {
  constexpr int FPL = F / 64;
  __shared__ float ls_alpha[4][64 * H];
  __shared__ int ls_src[4][64];
  const int wave = threadIdx.x >> 6, lane = threadIdx.x & 63;
  float* const la = ls_alpha[wave];
  int* const lsrc = ls_src[wave];

  for (int n = blockIdx.x * 4 + wave; n < N; n += gridDim.x * 4) {
    const int o0 = off[n];
    const int deg = off[n + 1] - o0;
    float aidn[H];
    loadH<H>(aid + (size_t)n * H, aidn);

    // ---- pass 1: online softmax stats (lane-parallel over edges) ----
    float m[H], s[H];
#pragma unroll
    for (int h = 0; h < H; ++h) { m[h] = -1e30f; s[h] = 0.f; }
    for (int i = lane; i < deg; i += 64) {
      int sr = ssrc[o0 + i];
      float aj[H], pv[H];
      loadH<H>(ajd + (size_t)sr * H, aj);
      loadH<H>(ep + (size_t)(o0 + i) * H, pv);
#pragma unroll
      for (int h = 0; h < H; ++h) {
        float sc = aj[h] + aidn[h] + pv[h];
        sc = sc > 0.f ? sc : 0.2f * sc;
        float mn = fmaxf(m[h], sc);
        s[h] = s[h] * __expf(m[h] - mn) + __expf(sc - mn);
        m[h] = mn;
      }
    }
#pragma unroll
    for (int o = 32; o > 0; o >>= 1) {
#pragma unroll
      for (int h = 0; h < H; ++h) {
        float m2 = __shfl_xor(m[h], o, 64);
        float s2 = __shfl_xor(s[h], o, 64);
        float mn = fmaxf(m[h], m2);
        s[h] = s[h] * __expf(m[h] - mn) + s2 * __expf(m2 - mn);
        m[h] = mn;
      }
    }
    float inv[H];
#pragma unroll
    for (int h = 0; h < H; ++h) inv[h] = 1.f / (s[h] + 1e-16f);

    // ---- pass 2: chunked alpha -> LDS, then 4-way unrolled gather+FMA ----
    float acc[H][FPL];
#pragma unroll
    for (int h = 0; h < H; ++h)
#pragma unroll
      for (int c = 0; c < FPL; ++c) acc[h][c] = 0.f;

    for (int base = 0; base < deg; base += 64) {
      const int cnt = min(64, deg - base);
      if (lane < cnt) {
        int i = base + lane;
        int sr = ssrc[o0 + i];
        lsrc[lane] = sr;
        float aj[H], pv[H];
        loadH<H>(ajd + (size_t)sr * H, aj);
        loadH<H>(ep + (size_t)(o0 + i) * H, pv);
#pragma unroll
        for (int h = 0; h < H; ++h) {
          float sc = aj[h] + aidn[h] + pv[h];
          sc = sc > 0.f ? sc : 0.2f * sc;
          la[lane * H + h] = __expf(sc - m[h]) * inv[h];
        }
      }
      asm volatile("s_waitcnt lgkmcnt(0)" ::: "memory");

      int j = 0;
      for (; j + 4 <= cnt; j += 4) {
        int srj[4];
        float av[4][H];
#pragma unroll
        for (int u = 0; u < 4; ++u) {
          srj[u] = lsrc[j + u];
          loadH<H>(la + (j + u) * H, av[u]);
        }
        float v[4][FPL];
#pragma unroll
        for (int u = 0; u < 4; ++u) {
          const float* hr = hin + (size_t)srj[u] * F + lane;
#pragma unroll
          for (int c = 0; c < FPL; ++c) v[u][c] = hr[c * 64];
        }
#pragma unroll
        for (int u = 0; u < 4; ++u)
#pragma unroll
          for (int h = 0; h < H; ++h)
#pragma unroll
            for (int c = 0; c < FPL; ++c)
              acc[h][c] = fmaf(av[u][h], v[u][c], acc[h][c]);
      }
      for (; j < cnt; ++j) {
        int sr = lsrc[j];
        float av[H];
        loadH<H>(la + j * H, av);
        const float* hr = hin + (size_t)sr * F + lane;
#pragma unroll
        for (int h = 0; h < H; ++h)
#pragma unroll
          for (int c = 0; c < FPL; ++c)
            acc[h][c] = fmaf(av[h], hr[c * 64], acc[h][c]);
      }
    }

    float* ob = outbuf + (size_t)n * (H * F);
#pragma unroll
    for (int h = 0; h < H; ++h)
#pragma unroll
      for (int c = 0; c < FPL; ++c) {
        float v = acc[h][c];
        if (ELU_OUT) v = (v > 0.f) ? v : expm1f(v);
        ob[h * F + c * 64 + lane] = v;
      }
  }
}

// ---------------- post GEMM (layer 2): out[n, h*64+j] = agg[n,h,:] @ W[:, h*64+j] ----------------
// Weights live in per-thread registers (thread owns output column j).

template <int F, int H, bool ELU_ACT>
__global__ __launch_bounds__(256) void k_post_reg(const float* __restrict__ agg,
                                                  const float* __restrict__ W,
                                                  float* __restrict__ out, int N) {
  constexpr int CO = H * 64;
  constexpr int NPB = 256 / CO;       // nodes per block-iteration
  const int tid = threadIdx.x;
  const int wave = tid >> 6;
  const int lane = tid & 63;
  const int sub = wave / H;           // node sub-index within block
  const int h = wave % H;
  const int j = h * 64 + lane;        // output column
  float w[F];
#pragma unroll
  for (int k = 0; k < F; ++k) w[k] = W[(size_t)k * CO + j];
  for (int n = blockIdx.x * NPB + sub; n < N; n += gridDim.x * NPB) {
    const float* ag = agg + (size_t)n * (H * F) + (size_t)h * F;
    float a = 0.f;
#pragma unroll
    for (int k = 0; k < F; ++k) a = fmaf(ag[k], w[k], a);
    if (ELU_ACT) a = (a > 0.f) ? a : expm1f(a);
    out[(size_t)n * CO + j] = a;
  }
}

// ---------------- launch ----------------

extern "C" void kernel_launch(void* const* d_in, const int* in_sizes, int n_in,
                              void* d_out, int out_size, void* d_ws, size_t ws_size,
                              hipStream_t stream) {
  const float* x    = (const float*)d_in[0];
  const int*   ei   = (const int*)d_in[1];
  const float* ea   = (const float*)d_in[2];
  const float* W0   = (const float*)d_in[3];
  const float* We0  = (const float*)d_in[4];
  const float* att0 = (const float*)d_in[5];
  const float* W1   = (const float*)d_in[6];
  const float* We1  = (const float*)d_in[7];
  const float* att1 = (const float*)d_in[8];
  const float* W2   = (const float*)d_in[9];
  const float* We2  = (const float*)d_in[10];
  const float* att2 = (const float*)d_in[11];
  float* out = (float*)d_out;

  const int N = in_sizes[0] / 128;   // 50000
  const int E = in_sizes[2] / 16;    // 800000

  char* p = (char*)d_ws;
  auto alloc = [&](size_t bytes) {
    char* r = p;
    p += (bytes + 255) & ~(size_t)255;
    return r;
  };
  int*   flag = (int*)  alloc(sizeof(int));
  int*   off  = (int*)  alloc((size_t)(N + 1) * sizeof(int));
  int*   cur  = (int*)  alloc((size_t)N * sizeof(int));
  int*   pos  = (int*)  alloc((size_t)E * sizeof(int));
  int*   ssrc = (int*)  alloc((size_t)E * sizeof(int));
  bf16x8* B1  = (bf16x8*)alloc(24 * 64 * sizeof(bf16x8));
  bf16x8* B2  = (bf16x8*)alloc(24 * 64 * sizeof(bf16x8));
  float* avec = (float*)alloc(384 * sizeof(float));
  float* waj2 = (float*)alloc(256 * sizeof(float));
  float* wai2 = (float*)alloc(256 * sizeof(float));
  float* ajdA = (float*)alloc((size_t)N * sizeof(float));
  float* aidA = (float*)alloc((size_t)N * sizeof(float));
  float* ajd2 = (float*)alloc((size_t)N * 4 * sizeof(float));
  float* aid2 = (float*)alloc((size_t)N * 4 * sizeof(float));
  float* ep0  = (float*)alloc((size_t)E * sizeof(float));
  float* ep1  = (float*)alloc((size_t)E * sizeof(float));
  float* ep2  = (float*)alloc((size_t)E * 4 * sizeof(float));
  float* xh0  = (float*)alloc((size_t)N * 64 * sizeof(float));
  float* h1   = (float*)alloc((size_t)N * 64 * sizeof(float));
  float* xh1  = (float*)alloc((size_t)N * 64 * sizeof(float));
  float* h2   = (float*)alloc((size_t)N * 64 * sizeof(float));
  float* aggL2= (float*)alloc((size_t)N * 256 * sizeof(float));

  const int eb = (E + THR - 1) / THR;
  const int nb = (N + THR - 1) / THR;
  const int ab = (N + 3) / 4;
  const int gb = min(ab, 2048);

  hipMemsetAsync(flag, 0, sizeof(int), stream);
  hipMemsetAsync(cur, 0, (size_t)N * sizeof(int), stream);

  k_detect<<<16, THR, 0, stream>>>(ei, flag);
  k_count<<<eb, THR, 0, stream>>>(ei, flag, cur, E);
  k_scan<<<1, 1024, 0, stream>>>(cur, off, N);
  k_scatter<<<eb, THR, 0, stream>>>(ei, flag, cur, pos, ssrc, E);

  k_prep_b<<<8, THR, 0, stream>>>(We0, We1, We2, att0, att1, att2, B1, B2, avec);
  // 256 edges per block (4 waves x 64 edges)
  k_ep_mfma<<<(E + 255) / 256, THR, 0, stream>>>(ea, B1, B2, avec, pos,
                                                 ep0, ep1, ep2, E);

  // layer 0: xh0 = x@W0 (+ fused a_j/a_i dots), aggregate in output space, ELU fused
  k_gemm_nh<128><<<gb, THR, 0, stream>>>(x, W0, att0, xh0, ajdA, aidA, N);
  k_attn_agg<64, 1, true><<<ab, THR, 0, stream>>>(off, ssrc, xh0, ajdA, aidA, ep0, h1, N);

  // layer 1: xh1 = h1@W1, aggregate, ELU fused
  k_gemm_nh<64><<<gb, THR, 0, stream>>>(h1, W1, att1, xh1, ajdA, aidA, N);
  k_attn_agg<64, 1, true><<<ab, THR, 0, stream>>>(off, ssrc, xh1, ajdA, aidA, ep1, h2, N);

  // layer 2: input-space aggregation (64 < 4*64), then post GEMM
  k_fold_att<<<1, 256, 0, stream>>>(W2, att2, waj2, wai2, 64, 4);
  k_node_dots<64, 4><<<nb, THR, 0, stream>>>(h2, waj2, wai2, ajd2, aid2, N);
  k_attn_agg<64, 4, false><<<ab, THR, 0, stream>>>(off, ssrc, h2, ajd2, aid2, ep2, aggL2, N);
  k_post_reg<64, 4, false><<<1024, THR, 0, stream>>>(aggL2, W2, out, N);
}

// Round 11
// 630.917 us; speedup vs baseline: 1.3474x; 1.1021x over previous
//
#include <hip/hip_runtime.h>
#include <math.h>

#define THR 256

typedef __attribute__((ext_vector_type(8))) short bf16x8;
typedef __attribute__((ext_vector_type(4))) float f32x4;

// ---------------- CSR build ----------------

// Detect whether edge_index buffer is int64 (high words all zero) or int32.
__global__ void k_detect(const int* __restrict__ w, int* __restrict__ flag) {
  int i = blockIdx.x * blockDim.x + threadIdx.x;
  if (i < 4096) {
    if (w[2 * i + 1] != 0) atomicOr(flag, 1);
  }
}

__device__ __forceinline__ int load_idx(const int* __restrict__ w, int pos, int is32) {
  return is32 ? w[pos] : w[2 * pos];
}

__global__ void k_count(const int* __restrict__ ei, const int* __restrict__ flag,
                        int* __restrict__ cnt, int E) {
  int e = blockIdx.x * blockDim.x + threadIdx.x;
  if (e < E) {
    int is32 = *flag;
    int d = load_idx(ei, E + e, is32);
    atomicAdd(&cnt[d], 1);
  }
}

__global__ __launch_bounds__(1024) void k_scan(int* __restrict__ cnt_cur, int* __restrict__ off, int n) {
  __shared__ int part[1024];
  int tid = threadIdx.x;
  int chunk = (n + 1023) / 1024;
  int s0 = tid * chunk;
  int s1 = min(s0 + chunk, n);
  int s = 0;
  for (int i = s0; i < s1; ++i) s += cnt_cur[i];
  part[tid] = s;
  __syncthreads();
  for (int d = 1; d < 1024; d <<= 1) {
    int v = (tid >= d) ? part[tid - d] : 0;
    __syncthreads();
    part[tid] += v;
    __syncthreads();
  }
  int excl = (tid == 0) ? 0 : part[tid - 1];
  for (int i = s0; i < s1; ++i) {
    int c = cnt_cur[i];
    off[i] = excl;
    cnt_cur[i] = excl;   // cursor copy for scatter
    excl += c;
  }
  if (tid == 1023) off[n] = part[1023];
}

__global__ void k_scatter(const int* __restrict__ ei, const int* __restrict__ flag,
                          int* __restrict__ cur, int* __restrict__ pos,
                          int* __restrict__ ssrc, int E) {
  int e = blockIdx.x * blockDim.x + threadIdx.x;
  if (e < E) {
    int is32 = *flag;
    int d = load_idx(ei, E + e, is32);
    int s = load_idx(ei, e, is32);
    int p = atomicAdd(&cur[d], 1);
    pos[e] = p;
    ssrc[p] = s;
  }
}

// ---------------- weight prep (layer 2 only) ----------------

__global__ void k_fold_att(const float* __restrict__ W, const float* __restrict__ att,
                           float* __restrict__ waj, float* __restrict__ wai,
                           int Cin, int H) {
  int i = blockIdx.x * blockDim.x + threadIdx.x;
  if (i >= Cin * H) return;
  int k = i / H, h = i % H;
  float sj = 0.f, si = 0.f;
  for (int d = 0; d < 64; ++d) {
    float w = W[k * (H * 64) + h * 64 + d];
    sj = fmaf(w, att[h * 192 + d], sj);
    si = fmaf(w, att[h * 192 + 64 + d], si);
  }
  waj[k * H + h] = sj;
  wai[k * H + h] = si;
}

template <int CIN, int H>
__global__ void k_node_dots(const float* __restrict__ xin, const float* __restrict__ waj,
                            const float* __restrict__ wai, float* __restrict__ ajd,
                            float* __restrict__ aid, int N) {
  int n = blockIdx.x * blockDim.x + threadIdx.x;
  if (n >= N) return;
  float sj[H], si[H];
#pragma unroll
  for (int h = 0; h < H; ++h) { sj[h] = 0.f; si[h] = 0.f; }
  const float* xr = xin + (size_t)n * CIN;
#pragma unroll 4
  for (int k = 0; k < CIN; ++k) {
    float xv = xr[k];
#pragma unroll
    for (int h = 0; h < H; ++h) {
      sj[h] = fmaf(xv, waj[k * H + h], sj[h]);
      si[h] = fmaf(xv, wai[k * H + h], si[h]);
    }
  }
#pragma unroll
  for (int h = 0; h < H; ++h) {
    ajd[(size_t)n * H + h] = sj[h];
    aid[(size_t)n * H + h] = si[h];
  }
}

// ---------------- per-node projection GEMM with fused att-dots (layers 0,1) ----------------
// xh[n,j] = sum_k xin[n,k] * W[k,j]   (64 output cols, lane j owns col j)
// ajd[n]  = sum_j xh[n,j] * att[j] ;  aid[n] = sum_j xh[n,j] * att[64+j]
template <int F>
__global__ __launch_bounds__(256) void k_gemm_nh(
    const float* __restrict__ xin, const float* __restrict__ W,
    const float* __restrict__ att, float* __restrict__ xh,
    float* __restrict__ ajd, float* __restrict__ aid, int N) {
  const int wave = threadIdx.x >> 6, lane = threadIdx.x & 63;
  float w[F];
#pragma unroll
  for (int k = 0; k < F; ++k) w[k] = W[k * 64 + lane];
  const float aj = att[lane], ai = att[64 + lane];
  for (int n = blockIdx.x * 4 + wave; n < N; n += gridDim.x * 4) {
    const float* xr = xin + (size_t)n * F;
    float a = 0.f;
#pragma unroll
    for (int k = 0; k < F; ++k) a = fmaf(xr[k], w[k], a);
    xh[(size_t)n * 64 + lane] = a;
    float sj = a * aj, si = a * ai;
#pragma unroll
    for (int o = 32; o > 0; o >>= 1) {
      sj += __shfl_xor(sj, o, 64);
      si += __shfl_xor(si, o, 64);
    }
    if (lane == 0) { ajd[n] = sj; aid[n] = si; }
  }
}

// ---------------- MFMA-based edge scalar ep ----------------

__device__ __forceinline__ unsigned short bf16_rne(float x) {
  unsigned int u = __float_as_uint(x);
  return (unsigned short)((u + 0x7FFFu + ((u >> 16) & 1u)) >> 16);
}

// Build weight fragments (A-operand of the swapped MFMA).
// Concat weight matrix We_cat: 16 x 384 (cols 0-63 We0, 64-127 We1, 128-383 We2).
// Split f32 = hi + lo (bf16 each). K=32 arrangement matches the edge fragments:
// k<16 pairs with edge-hi, k>=16 pairs with edge-lo. B1 = [Whi;Whi], B2 = [Wlo;0].
// Fragment layout (operand-symmetric): lane l holds row/col = T*16 + (l&15),
// k = (l>>4)*8 + j, j=0..7.  avec[384]: a_p coefficient per concat column.
__global__ void k_prep_b(const float* __restrict__ We0, const float* __restrict__ We1,
                         const float* __restrict__ We2,
                         const float* __restrict__ att0, const float* __restrict__ att1,
                         const float* __restrict__ att2,
                         bf16x8* __restrict__ B1, bf16x8* __restrict__ B2,
                         float* __restrict__ avec) {
  int i = blockIdx.x * blockDim.x + threadIdx.x;
  if (i < 24 * 64) {
    int T = i >> 6, l = i & 63;
    int col = T * 16 + (l & 15);
    int grp = l >> 4;
    bf16x8 b1, b2;
#pragma unroll
    for (int j = 0; j < 8; ++j) {
      int kk = grp * 8 + j;     // 0..31
      int ks = kk & 15;         // source k (both halves use same Whi)
      float w;
      if (col < 64)        w = We0[ks * 64 + col];
      else if (col < 128)  w = We1[ks * 64 + (col - 64)];
      else                 w = We2[ks * 256 + (col - 128)];
      unsigned short hi = bf16_rne(w);
      float hif = __uint_as_float((unsigned int)hi << 16);
      unsigned short lo = bf16_rne(w - hif);
      b1[j] = (short)hi;
      b2[j] = (kk < 16) ? (short)lo : (short)0;
    }
    B1[i] = b1;
    B2[i] = b2;
  } else if (i < 24 * 64 + 384) {
    int col = i - 24 * 64;
    float a;
    if (col < 64)        a = att0[128 + col];
    else if (col < 128)  a = att1[128 + (col - 64)];
    else {
      int c = col - 128;
      a = att2[(c >> 6) * 192 + 128 + (c & 63)];
    }
    avec[col] = a;
  }
}

// One wave = 64 edges (4 edge fragments of 16, used as the MFMA *B* operand).
// A operand = weight tiles (d-outputs on the M side). D tile: col(lane&15)=edge,
// row(grp*4+reg)=d. The relu*a_p reduction over d is therefore in-register
// (4 FMAs/tile) + one 2-stage cross-group shfl per (seg,frag) — no 16-lane
// reduce, no serialized scatter. ep2 accumulates in a float4 across segs 2-5
// and stores once (no 4x write amplification).
__global__ __launch_bounds__(256) void k_ep_mfma(
    const float* __restrict__ ea, const bf16x8* __restrict__ B1,
    const bf16x8* __restrict__ B2, const float* __restrict__ avec,
    const int* __restrict__ pos, float* __restrict__ ep0,
    float* __restrict__ ep1, float* __restrict__ ep2, int E) {
  const int lane = threadIdx.x & 63;
  const int wv = threadIdx.x >> 6;
  const long e0 = ((long)blockIdx.x * 4 + wv) * 64;
  const int grp = lane >> 4;        // 0..3
  const int row = lane & 15;        // edge index within fragment (B: N-col)
  const int kc = (grp & 1) * 8;     // which 8 source-k's this lane group loads
  const bool lo_grp = grp >= 2;     // groups 2,3 carry the lo halves (k 16..31)

  // ---- edge fragments (B operand) ----
  bf16x8 Bf[4];
#pragma unroll
  for (int f = 0; f < 4; ++f) {
    long e = e0 + f * 16 + row;
    if (e >= E) e = E - 1;          // clamp; stores guarded later
    const float* ar = ea + e * 16 + kc;
    float4 u0 = *reinterpret_cast<const float4*>(ar);
    float4 u1 = *reinterpret_cast<const float4*>(ar + 4);
    float v0 = u0.x, v1 = u0.y, v2 = u0.z, v3 = u0.w;
    float v4 = u1.x, v5 = u1.y, v6 = u1.z, v7 = u1.w;
    bf16x8 a;
#define CVT(J, V)                                                        \
    {                                                                    \
      unsigned short hi = bf16_rne(V);                                   \
      float hif = __uint_as_float((unsigned int)hi << 16);               \
      unsigned short lo = bf16_rne((V) - hif);                           \
      a[J] = (short)(lo_grp ? lo : hi);                                  \
    }
    CVT(0, v0) CVT(1, v1) CVT(2, v2) CVT(3, v3)
    CVT(4, v4) CVT(5, v5) CVT(6, v6) CVT(7, v7)
#undef CVT
    Bf[f] = a;
  }

  // ---- CSR positions (hoisted; used by lanes 0..15) ----
  int pf[4];
#pragma unroll
  for (int f = 0; f < 4; ++f) {
    long e = e0 + f * 16 + row;
    pf[f] = pos[e < E ? e : (E - 1)];
  }

  float4 v2acc[4];

  // ---- 6 segments x 4 tiles, d on the M (row) side ----
#pragma unroll
  for (int seg = 0; seg < 6; ++seg) {
    float sp0 = 0.f, sp1 = 0.f, sp2 = 0.f, sp3 = 0.f;
#pragma unroll
    for (int tt = 0; tt < 4; ++tt) {
      const int T = seg * 4 + tt;
      bf16x8 a1 = B1[T * 64 + lane];
      bf16x8 a2 = B2[T * 64 + lane];
      // a_p values for this lane's 4 d-rows: d = T*16 + grp*4 + r
      float4 av = *reinterpret_cast<const float4*>(avec + T * 16 + (grp << 2));
#define EPTILE(SP, F)                                                     \
      {                                                                   \
        f32x4 acc = {0.f, 0.f, 0.f, 0.f};                                 \
        acc = __builtin_amdgcn_mfma_f32_16x16x32_bf16(a1, Bf[F], acc, 0, 0, 0); \
        acc = __builtin_amdgcn_mfma_f32_16x16x32_bf16(a2, Bf[F], acc, 0, 0, 0); \
        SP = fmaf(fmaxf(acc[0], 0.f), av.x, SP);                          \
        SP = fmaf(fmaxf(acc[1], 0.f), av.y, SP);                          \
        SP = fmaf(fmaxf(acc[2], 0.f), av.z, SP);                          \
        SP = fmaf(fmaxf(acc[3], 0.f), av.w, SP);                          \
      }
      EPTILE(sp0, 0) EPTILE(sp1, 1) EPTILE(sp2, 2) EPTILE(sp3, 3)
#undef EPTILE
    }
    // combine the 4 lane-groups (each holds a quarter of the 64 d's)
    sp0 += __shfl_xor(sp0, 16, 64); sp0 += __shfl_xor(sp0, 32, 64);
    sp1 += __shfl_xor(sp1, 16, 64); sp1 += __shfl_xor(sp1, 32, 64);
    sp2 += __shfl_xor(sp2, 16, 64); sp2 += __shfl_xor(sp2, 32, 64);
    sp3 += __shfl_xor(sp3, 16, 64); sp3 += __shfl_xor(sp3, 32, 64);

    float spf[4] = {sp0, sp1, sp2, sp3};
    if (seg == 0) {
      if (lane < 16) {
#pragma unroll
        for (int f = 0; f < 4; ++f)
          if (e0 + f * 16 + lane < E) ep0[pf[f]] = spf[f];
      }
    } else if (seg == 1) {
      if (lane < 16) {
#pragma unroll
        for (int f = 0; f < 4; ++f)
          if (e0 + f * 16 + lane < E) ep1[pf[f]] = spf[f];
      }
    } else {
#pragma unroll
      for (int f = 0; f < 4; ++f) {
        if (seg == 2) v2acc[f].x = spf[f];
        if (seg == 3) v2acc[f].y = spf[f];
        if (seg == 4) v2acc[f].z = spf[f];
        if (seg == 5) v2acc[f].w = spf[f];
      }
    }
  }
  if (lane < 16) {
#pragma unroll
    for (int f = 0; f < 4; ++f)
      if (e0 + f * 16 + lane < E)
        reinterpret_cast<float4*>(ep2)[pf[f]] = v2acc[f];
  }
}

// ---------------- fused attention softmax + aggregate ----------------

template <int H>
__device__ __forceinline__ void loadH(const float* __restrict__ p, float* v) {
  if constexpr (H == 4) {
    float4 t = *reinterpret_cast<const float4*>(p);
    v[0] = t.x; v[1] = t.y; v[2] = t.z; v[3] = t.w;
  } else {
    v[0] = *p;
  }
}

// one wave per node, all H heads together.
// agg[n, h*F + f] = sum_e alpha_{e,h} * hin[src_e, f]   (+ optional ELU)
template <int F, int H, bool ELU_OUT>
__global__ __launch_bounds__(256) void k_attn_agg(
    const int* __restrict__ off, const int* __restrict__ ssrc,
    const float* __restrict__ hin, const float* __restrict__ ajd,
    const float* __restrict__ aid, const float* __restrict__ ep,
    float* __restrict__ outbuf, int N) {
  constexpr int FPL = F / 64;
  __shared__ float ls_alpha[4][64 * H];
  __shared__ int ls_src[4][64];
  const int wave = threadIdx.x >> 6, lane = threadIdx.x & 63;
  float* const la = ls_alpha[wave];
  int* const lsrc = ls_src[wave];

  for (int n = blockIdx.x * 4 + wave; n < N; n += gridDim.x * 4) {
    const int o0 = off[n];
    const int deg = off[n + 1] - o0;
    float aidn[H];
    loadH<H>(aid + (size_t)n * H, aidn);

    // ---- pass 1: online softmax stats (lane-parallel over edges) ----
    float m[H], s[H];
#pragma unroll
    for (int h = 0; h < H; ++h) { m[h] = -1e30f; s[h] = 0.f; }
    for (int i = lane; i < deg; i += 64) {
      int sr = ssrc[o0 + i];
      float aj[H], pv[H];
      loadH<H>(ajd + (size_t)sr * H, aj);
      loadH<H>(ep + (size_t)(o0 + i) * H, pv);
#pragma unroll
      for (int h = 0; h < H; ++h) {
        float sc = aj[h] + aidn[h] + pv[h];
        sc = sc > 0.f ? sc : 0.2f * sc;
        float mn = fmaxf(m[h], sc);
        s[h] = s[h] * __expf(m[h] - mn) + __expf(sc - mn);
        m[h] = mn;
      }
    }
#pragma unroll
    for (int o = 32; o > 0; o >>= 1) {
#pragma unroll
      for (int h = 0; h < H; ++h) {
        float m2 = __shfl_xor(m[h], o, 64);
        float s2 = __shfl_xor(s[h], o, 64);
        float mn = fmaxf(m[h], m2);
        s[h] = s[h] * __expf(m[h] - mn) + s2 * __expf(m2 - mn);
        m[h] = mn;
      }
    }
    float inv[H];
#pragma unroll
    for (int h = 0; h < H; ++h) inv[h] = 1.f / (s[h] + 1e-16f);

    // ---- pass 2: chunked alpha -> LDS, then 4-way unrolled gather+FMA ----
    float acc[H][FPL];
#pragma unroll
    for (int h = 0; h < H; ++h)
#pragma unroll
      for (int c = 0; c < FPL; ++c) acc[h][c] = 0.f;

    for (int base = 0; base < deg; base += 64) {
      const int cnt = min(64, deg - base);
      if (lane < cnt) {
        int i = base + lane;
        int sr = ssrc[o0 + i];
        lsrc[lane] = sr;
        float aj[H], pv[H];
        loadH<H>(ajd + (size_t)sr * H, aj);
        loadH<H>(ep + (size_t)(o0 + i) * H, pv);
#pragma unroll
        for (int h = 0; h < H; ++h) {
          float sc = aj[h] + aidn[h] + pv[h];
          sc = sc > 0.f ? sc : 0.2f * sc;
          la[lane * H + h] = __expf(sc - m[h]) * inv[h];
        }
      }
      asm volatile("s_waitcnt lgkmcnt(0)" ::: "memory");

      int j = 0;
      for (; j + 4 <= cnt; j += 4) {
        int srj[4];
        float av[4][H];
#pragma unroll
        for (int u = 0; u < 4; ++u) {
          srj[u] = lsrc[j + u];
          loadH<H>(la + (j + u) * H, av[u]);
        }
        float v[4][FPL];
#pragma unroll
        for (int u = 0; u < 4; ++u) {
          const float* hr = hin + (size_t)srj[u] * F + lane;
#pragma unroll
          for (int c = 0; c < FPL; ++c) v[u][c] = hr[c * 64];
        }
#pragma unroll
        for (int u = 0; u < 4; ++u)
#pragma unroll
          for (int h = 0; h < H; ++h)
#pragma unroll
            for (int c = 0; c < FPL; ++c)
              acc[h][c] = fmaf(av[u][h], v[u][c], acc[h][c]);
      }
      for (; j < cnt; ++j) {
        int sr = lsrc[j];
        float av[H];
        loadH<H>(la + j * H, av);
        const float* hr = hin + (size_t)sr * F + lane;
#pragma unroll
        for (int h = 0; h < H; ++h)
#pragma unroll
          for (int c = 0; c < FPL; ++c)
            acc[h][c] = fmaf(av[h], hr[c * 64], acc[h][c]);
      }
    }

    float* ob = outbuf + (size_t)n * (H * F);
#pragma unroll
    for (int h = 0; h < H; ++h)
#pragma unroll
      for (int c = 0; c < FPL; ++c) {
        float v = acc[h][c];
        if (ELU_OUT) v = (v > 0.f) ? v : expm1f(v);
        ob[h * F + c * 64 + lane] = v;
      }
  }
}

// ---------------- post GEMM (layer 2): out[n, h*64+j] = agg[n,h,:] @ W[:, h*64+j] ----------------
// Weights live in per-thread registers (thread owns output column j).

template <int F, int H, bool ELU_ACT>
__global__ __launch_bounds__(256) void k_post_reg(const float* __restrict__ agg,
                                                  const float* __restrict__ W,
                                                  float* __restrict__ out, int N) {
  constexpr int CO = H * 64;
  constexpr int NPB = 256 / CO;       // nodes per block-iteration
  const int tid = threadIdx.x;
  const int wave = tid >> 6;
  const int lane = tid & 63;
  const int sub = wave / H;           // node sub-index within block
  const int h = wave % H;
  const int j = h * 64 + lane;        // output column
  float w[F];
#pragma unroll
  for (int k = 0; k < F; ++k) w[k] = W[(size_t)k * CO + j];
  for (int n = blockIdx.x * NPB + sub; n < N; n += gridDim.x * NPB) {
    const float* ag = agg + (size_t)n * (H * F) + (size_t)h * F;
    float a = 0.f;
#pragma unroll
    for (int k = 0; k < F; ++k) a = fmaf(ag[k], w[k], a);
    if (ELU_ACT) a = (a > 0.f) ? a : expm1f(a);
    out[(size_t)n * CO + j] = a;
  }
}

// ---------------- launch ----------------

extern "C" void kernel_launch(void* const* d_in, const int* in_sizes, int n_in,
                              void* d_out, int out_size, void* d_ws, size_t ws_size,
                              hipStream_t stream) {
  const float* x    = (const float*)d_in[0];
  const int*   ei   = (const int*)d_in[1];
  const float* ea   = (const float*)d_in[2];
  const float* W0   = (const float*)d_in[3];
  const float* We0  = (const float*)d_in[4];
  const float* att0 = (const float*)d_in[5];
  const float* W1   = (const float*)d_in[6];
  const float* We1  = (const float*)d_in[7];
  const float* att1 = (const float*)d_in[8];
  const float* W2   = (const float*)d_in[9];
  const float* We2  = (const float*)d_in[10];
  const float* att2 = (const float*)d_in[11];
  float* out = (float*)d_out;

  const int N = in_sizes[0] / 128;   // 50000
  const int E = in_sizes[2] / 16;    // 800000

  char* p = (char*)d_ws;
  auto alloc = [&](size_t bytes) {
    char* r = p;
    p += (bytes + 255) & ~(size_t)255;
    return r;
  };
  int*   flag = (int*)  alloc(sizeof(int));
  int*   off  = (int*)  alloc((size_t)(N + 1) * sizeof(int));
  int*   cur  = (int*)  alloc((size_t)N * sizeof(int));
  int*   pos  = (int*)  alloc((size_t)E * sizeof(int));
  int*   ssrc = (int*)  alloc((size_t)E * sizeof(int));
  bf16x8* B1  = (bf16x8*)alloc(24 * 64 * sizeof(bf16x8));
  bf16x8* B2  = (bf16x8*)alloc(24 * 64 * sizeof(bf16x8));
  float* avec = (float*)alloc(384 * sizeof(float));
  float* waj2 = (float*)alloc(256 * sizeof(float));
  float* wai2 = (float*)alloc(256 * sizeof(float));
  float* ajdA = (float*)alloc((size_t)N * sizeof(float));
  float* aidA = (float*)alloc((size_t)N * sizeof(float));
  float* ajd2 = (float*)alloc((size_t)N * 4 * sizeof(float));
  float* aid2 = (float*)alloc((size_t)N * 4 * sizeof(float));
  float* ep0  = (float*)alloc((size_t)E * sizeof(float));
  float* ep1  = (float*)alloc((size_t)E * sizeof(float));
  float* ep2  = (float*)alloc((size_t)E * 4 * sizeof(float));
  float* xh0  = (float*)alloc((size_t)N * 64 * sizeof(float));
  float* h1   = (float*)alloc((size_t)N * 64 * sizeof(float));
  float* xh1  = (float*)alloc((size_t)N * 64 * sizeof(float));
  float* h2   = (float*)alloc((size_t)N * 64 * sizeof(float));
  float* aggL2= (float*)alloc((size_t)N * 256 * sizeof(float));

  const int eb = (E + THR - 1) / THR;
  const int nb = (N + THR - 1) / THR;
  const int ab = (N + 3) / 4;
  const int gb = min(ab, 2048);

  hipMemsetAsync(flag, 0, sizeof(int), stream);
  hipMemsetAsync(cur, 0, (size_t)N * sizeof(int), stream);

  k_detect<<<16, THR, 0, stream>>>(ei, flag);
  k_count<<<eb, THR, 0, stream>>>(ei, flag, cur, E);
  k_scan<<<1, 1024, 0, stream>>>(cur, off, N);
  k_scatter<<<eb, THR, 0, stream>>>(ei, flag, cur, pos, ssrc, E);

  k_prep_b<<<8, THR, 0, stream>>>(We0, We1, We2, att0, att1, att2, B1, B2, avec);
  // 256 edges per block (4 waves x 64 edges)
  k_ep_mfma<<<(E + 255) / 256, THR, 0, stream>>>(ea, B1, B2, avec, pos,
                                                 ep0, ep1, ep2, E);

  // layer 0: xh0 = x@W0 (+ fused a_j/a_i dots), aggregate in output space, ELU fused
  k_gemm_nh<128><<<gb, THR, 0, stream>>>(x, W0, att0, xh0, ajdA, aidA, N);
  k_attn_agg<64, 1, true><<<ab, THR, 0, stream>>>(off, ssrc, xh0, ajdA, aidA, ep0, h1, N);

  // layer 1: xh1 = h1@W1, aggregate, ELU fused
  k_gemm_nh<64><<<gb, THR, 0, stream>>>(h1, W1, att1, xh1, ajdA, aidA, N);
  k_attn_agg<64, 1, true><<<ab, THR, 0, stream>>>(off, ssrc, xh1, ajdA, aidA, ep1, h2, N);

  // layer 2: input-space aggregation (64 < 4*64), then post GEMM
  k_fold_att<<<1, 256, 0, stream>>>(W2, att2, waj2, wai2, 64, 4);
  k_node_dots<64, 4><<<nb, THR, 0, stream>>>(h2, waj2, wai2, ajd2, aid2, N);
  k_attn_agg<64, 4, false><<<ab, THR, 0, stream>>>(off, ssrc, h2, ajd2, aid2, ep2, aggL2, N);
  k_post_reg<64, 4, false><<<1024, THR, 0, stream>>>(aggL2, W2, out, N);
}